// Round 6
// baseline (91302.081 us; speedup 1.0000x reference)
//
#include <hip/hip_runtime.h>
#include <hip/hip_bf16.h>
#include <math.h>

#define NN 2000
#define DD 16
#define BB 64
#define TT 12
#define HH 64
#define MR 4000   // rows of stacked M = [A ; 2A^2 - I]
#define SCL 2048.0f
#define ISCL (1.0f / 2048.0f)

typedef _Float16 f16;
typedef __attribute__((ext_vector_type(8))) _Float16 frag8h;  // 8 f16 = 4 VGPRs
typedef __attribute__((ext_vector_type(4))) float floatx4;

__device__ inline float fin(float v) {
  return (v == v && v > -1e30f && v < 1e30f) ? v : 0.f;
}
__device__ inline float sigmoid_safe(float x) {
  float e = expf(-fabsf(x));
  float s = 1.f / (1.f + e);
  return x >= 0.f ? s : 1.f - s;
}
__device__ inline float tanh_safe(float x) {
  float e = expf(-2.f * fabsf(x));
  float r = (1.f - e) / (1.f + e);
  return x >= 0.f ? r : -r;
}
// split v = hi + lo/2048, hi/lo f16
__device__ inline void split16(float v, f16& hi, f16& lo) {
  hi = (f16)v;
  lo = (f16)((v - (float)hi) * SCL);
}
// async global->LDS 16B: lands at (wave-uniform) l + lane*16
__device__ inline void gll16(const void* g, void* l) {
  __builtin_amdgcn_global_load_lds((const __attribute__((address_space(1))) void*)g,
                                   (__attribute__((address_space(3))) void*)l, 16, 0, 0);
}

__global__ void kzero(float* p, int n) {
  int i = blockIdx.x * 256 + threadIdx.x;
  if (i < n) p[i] = 0.f;
}

// ---- A = softmax(relu(E E^T), axis=1); all f32 ----
__global__ __launch_bounds__(256) void ka(const float* __restrict__ E,
                                          float* __restrict__ A) {
  __shared__ float s[NN];
  __shared__ float red[256];
  int n = blockIdx.x;
  float en[DD];
#pragma unroll
  for (int d = 0; d < DD; ++d) en[d] = fin(E[n * DD + d]);
  float lmax = 0.f;
  for (int m = threadIdx.x; m < NN; m += 256) {
    float acc = 0.f;
#pragma unroll
    for (int d = 0; d < DD; ++d) acc += en[d] * fin(E[m * DD + d]);
    acc = fmaxf(acc, 0.f);
    s[m] = acc;
    lmax = fmaxf(lmax, acc);
  }
  red[threadIdx.x] = lmax;
  __syncthreads();
  for (int w = 128; w > 0; w >>= 1) {
    if (threadIdx.x < w) red[threadIdx.x] = fmaxf(red[threadIdx.x], red[threadIdx.x + w]);
    __syncthreads();
  }
  float mx = red[0];
  __syncthreads();
  float lsum = 0.f;
  for (int m = threadIdx.x; m < NN; m += 256) {
    float e = expf(s[m] - mx);
    s[m] = e;
    lsum += e;
  }
  red[threadIdx.x] = lsum;
  __syncthreads();
  for (int w = 128; w > 0; w >>= 1) {
    if (threadIdx.x < w) red[threadIdx.x] += red[threadIdx.x + w];
    __syncthreads();
  }
  float inv = 1.f / red[0];
  for (int m = threadIdx.x; m < NN; m += 256) A[(size_t)n * NN + m] = s[m] * inv;
}

// ---- C(NN x cols) = A @ V ; f32, 64x64 tile (prologue only, for A^2) ----
#define TM 64
#define TK 32
__global__ __launch_bounds__(256) void kg(const float* __restrict__ A,
                                          const float* __restrict__ V,
                                          float* __restrict__ C, int cols) {
  __shared__ float As[TK][TM + 1];
  __shared__ float Bs[TK][TM + 1];
  int r0 = blockIdx.x * TM;
  int c0 = blockIdx.y * TM;
  int tid = threadIdx.x;
  int tx = tid % 16;
  int ty = tid / 16;
  float acc[4][4];
#pragma unroll
  for (int i = 0; i < 4; ++i)
#pragma unroll
    for (int j = 0; j < 4; ++j) acc[i][j] = 0.f;
  for (int k0 = 0; k0 < NN; k0 += TK) {
    for (int i = tid; i < TM * TK; i += 256) {
      int rr = i / TK, kk = i % TK;
      int gr = r0 + rr, gk = k0 + kk;
      As[kk][rr] = (gr < NN && gk < NN) ? A[(size_t)gr * NN + gk] : 0.f;
    }
    for (int i = tid; i < TK * TM; i += 256) {
      int kk = i / TM, cc = i % TM;
      int gk = k0 + kk, gc = c0 + cc;
      Bs[kk][cc] = (gk < NN && gc < cols) ? V[(size_t)gk * cols + gc] : 0.f;
    }
    __syncthreads();
#pragma unroll 4
    for (int kk = 0; kk < TK; ++kk) {
      float a[4], b[4];
#pragma unroll
      for (int i = 0; i < 4; ++i) a[i] = As[kk][ty * 4 + i];
#pragma unroll
      for (int j = 0; j < 4; ++j) b[j] = Bs[kk][tx * 4 + j];
#pragma unroll
      for (int i = 0; i < 4; ++i)
#pragma unroll
        for (int j = 0; j < 4; ++j) acc[i][j] += a[i] * b[j];
    }
    __syncthreads();
  }
#pragma unroll
  for (int i = 0; i < 4; ++i) {
    int gr = r0 + ty * 4 + i;
    if (gr >= NN) continue;
#pragma unroll
    for (int j = 0; j < 4; ++j) {
      int gc = c0 + tx * 4 + j;
      if (gc < cols) C[(size_t)gr * cols + gc] = acc[i][j];
    }
  }
}

// ---- build split M = [A ; 2A^2 - I] as f16 hi + lo/2048 ----
__global__ void ksplitM(const float* __restrict__ A, const float* __restrict__ A2,
                        f16* __restrict__ Mh, f16* __restrict__ Ml) {
  int i = blockIdx.x * 256 + threadIdx.x;
  if (i >= MR * NN) return;
  int m = i / NN;
  int k = i % NN;
  float v;
  if (m < NN) v = A[(size_t)m * NN + k];
  else {
    int mm = m - NN;
    v = 2.f * A2[(size_t)mm * NN + k] - (mm == k ? 1.f : 0.f);
  }
  f16 hi, lo;
  split16(v, hi, lo);
  Mh[i] = hi;
  Ml[i] = lo;
}

// ---- split+transpose: V f32 [2000][cols] -> Th/Tl f16 [cols][2000] ----
__global__ __launch_bounds__(256) void kconvT(const float* __restrict__ V,
                                              f16* __restrict__ Th,
                                              f16* __restrict__ Tl, int cols) {
  __shared__ float sh[32][33];
  int k0 = blockIdx.x * 32;
  int c0 = blockIdx.y * 32;
  int tx = threadIdx.x % 32;
  int ty = threadIdx.x / 32;  // 0..7
#pragma unroll
  for (int i = 0; i < 4; ++i) {
    int r = k0 + ty + i * 8;
    int c = c0 + tx;
    sh[ty + i * 8][tx] = (r < NN && c < cols) ? V[(size_t)r * cols + c] : 0.f;
  }
  __syncthreads();
#pragma unroll
  for (int i = 0; i < 4; ++i) {
    int cc = c0 + ty + i * 8;
    int kk = k0 + tx;
    if (cc < cols && kk < NN) {
      f16 hi, lo;
      split16(sh[tx][ty + i * 8], hi, lo);
      Th[(size_t)cc * NN + kk] = hi;
      Tl[(size_t)cc * NN + kk] = lo;
    }
  }
}

// ---- MFMA GEMM v7: C = (Mh + Ml/2048) @ (Bh + Bl/2048), dropping Ml@Bl.
// Theory (R1/R3/R4 probes): kmm is operand-TRAFFIC-bound (~5 TB/s from L3);
// latency/occupancy micro-structure is null. So: 256(M) x 128(N) block tile
// cuts per-call traffic 25% (nby*32MB + nbx*32MB: 2.06GB -> 1.55GB) while
// KEEPING 2 blocks/CU (R3's failure was 1-block lockstep):
//   4 waves (2M x 2N), per-wave 128x64 = acc[8][4] floatx4 = 128 VGPR
//   (single-acc operand-shift scheme, validated R4/R5: absmax 0.0195),
//   LDS 48KB single-buffer -> 2 blocks/CU = 96KB, 8 waves/CU (= baseline).
// K-order and per-output MFMA order unchanged -> absmax identical to R5.
#define KT 32
__global__ __launch_bounds__(256, 2) void kmm(const f16* __restrict__ Mh,
                                              const f16* __restrict__ Ml,
                                              const f16* __restrict__ Bh,
                                              const f16* __restrict__ Bl,
                                              float* __restrict__ C1,
                                              float* __restrict__ C2, int cols) {
  __shared__ __align__(16) f16 Ash[256 * KT];   // 16KB, regions 0..15 (16 rows each)
  __shared__ __align__(16) f16 Asl[256 * KT];   // 16KB
  __shared__ __align__(16) f16 Bsh[128 * KT];   // 8KB, regions 0..7
  __shared__ __align__(16) f16 Bsl[128 * KT];   // 8KB
  int tid = threadIdx.x;
  int lane = tid & 63;
  int wave = tid >> 6;  // 0..3
  int wr = wave >> 1;   // 0..1 (M half: 128 rows)
  int wc = wave & 1;    // 0..1 (N half: 64 cols)
  // XCD swizzle: bijective contiguous-chunk remap (m204) for L2 reuse.
  int gx = gridDim.x;
  int nwg = gx * gridDim.y;
  int wg = blockIdx.y * gx + blockIdx.x;
  int q = nwg >> 3, r = nwg & 7;
  int xcd = wg & 7, lid = wg >> 3;
  int swz = (xcd < r ? xcd * (q + 1) : r * (q + 1) + (xcd - r) * q) + lid;
  int bx = swz % gx;
  int by = swz / gx;
  floatx4 acc[8][4];
#pragma unroll
  for (int i = 0; i < 8; ++i)
#pragma unroll
    for (int j = 0; j < 4; ++j) acc[i][j] = (floatx4){0.f, 0.f, 0.f, 0.f};
  const frag8h zf = {0, 0, 0, 0, 0, 0, 0, 0};
  const f16 hscl = (f16)ISCL;   // exact power of two

  auto comp = [&]() {
    frag8h bh[4], bhd[4], blu[4];
#pragma unroll
    for (int ni = 0; ni < 4; ++ni) {
      int jc = wc * 4 + ni;
      frag8h b0 = *(const frag8h*)(&Bsh[jc * 512 + lane * 8]);
      frag8h b1 = *(const frag8h*)(&Bsl[jc * 512 + lane * 8]);
      bh[ni] = b0;
      bhd[ni] = b0 * hscl;   // exact exponent shift (normal range)
      blu[ni] = b1 * hscl;
    }
#pragma unroll
    for (int half = 0; half < 2; ++half) {
      frag8h ah[4], al[4];
#pragma unroll
      for (int m2 = 0; m2 < 4; ++m2) {
        int jr = wr * 8 + half * 4 + m2;           // A region 0..15
        ah[m2] = *(const frag8h*)(&Ash[jr * 512 + lane * 8]);
        al[m2] = *(const frag8h*)(&Asl[jr * 512 + lane * 8]);
      }
#pragma unroll
      for (int m2 = 0; m2 < 4; ++m2)
#pragma unroll
        for (int ni = 0; ni < 4; ++ni) {
          int mi = half * 4 + m2;
          acc[mi][ni] = __builtin_amdgcn_mfma_f32_16x16x32_f16(ah[m2], bh[ni], acc[mi][ni], 0, 0, 0);
          acc[mi][ni] = __builtin_amdgcn_mfma_f32_16x16x32_f16(ah[m2], blu[ni], acc[mi][ni], 0, 0, 0);
          acc[mi][ni] = __builtin_amdgcn_mfma_f32_16x16x32_f16(al[m2], bhd[ni], acc[mi][ni], 0, 0, 0);
        }
    }
  };

  const int lr = lane & 15;   // row within region this lane stages
  const int lq = lane >> 4;   // k-chunk this lane stages
  // 48 regions of 1KB: [Ash 0..15 | Asl 0..15 | Bsh 0..7 | Bsl 0..7].
  // Wave w stages regions 12w..12w+11 (addresses clamped -> uniform count).
  auto stage = [&](int k0) {
#pragma unroll
    for (int jj = 0; jj < 12; ++jj) {
      int g = wave * 12 + jj;          // wave-uniform 0..47
      size_t ko = (size_t)k0 + lq * 8;
      if (g < 32) {
        int j = g & 15;
        int gra = bx * 256 + j * 16 + lr;
        if (gra >= MR) gra = MR - 1;
        const f16* s = (g < 16) ? Mh : Ml;
        f16* d = ((g < 16) ? Ash : Asl) + j * 512;
        gll16(s + (size_t)gra * NN + ko, d);
      } else {
        int j = (g - 32) & 7;
        int grb = by * 128 + j * 16 + lr;
        if (grb >= cols) grb = cols - 1;
        const f16* s = (g < 40) ? Bh : Bl;
        f16* d = ((g < 40) ? Bsh : Bsl) + j * 512;
        gll16(s + (size_t)grb * NN + ko, d);
      }
    }
  };

  // fast path: full 32-k tiles via global_load_lds
  for (int k0 = 0; k0 + KT <= NN; k0 += KT) {
    stage(k0);
    __syncthreads();
    comp();
    __syncthreads();
  }
  // tail (k0 = 1984, 16 valid k): guarded VGPR staging, same slot layout
  {
    int k0 = (NN / KT) * KT;
    if (k0 < NN) {
      for (int c = tid; c < 48 * 64; c += 256) {
        int g = c >> 6;          // region 0..47
        int ll = c & 63;         // slot within region
        int qq = ll >> 4;
        int rr = ll & 15;
        int gk = k0 + qq * 8;
        bool kok = (gk + 8 <= NN);
        if (g < 32) {
          int j = g & 15;
          int gra = bx * 256 + j * 16 + rr;
          bool aok = kok && (gra < MR);
          size_t ga = (size_t)gra * NN + gk;
          f16* d = ((g < 16) ? Ash : Asl) + j * 512 + ll * 8;
          const f16* s = (g < 16) ? Mh : Ml;
          *(frag8h*)d = aok ? *(const frag8h*)(s + ga) : zf;
        } else {
          int j = (g - 32) & 7;
          int grb = by * 128 + j * 16 + rr;
          bool bok = kok && (grb < cols);
          size_t gb = (size_t)grb * NN + gk;
          f16* d = ((g < 40) ? Bsh : Bsl) + j * 512 + ll * 8;
          const f16* s = (g < 40) ? Bh : Bl;
          *(frag8h*)d = bok ? *(const frag8h*)(s + gb) : zf;
        }
      }
      __syncthreads();
      comp();
      __syncthreads();
    }
  }
  // store: C/D layout col = lane&15, row = (lane>>4)*4 + reg
#pragma unroll
  for (int mi = 0; mi < 8; ++mi) {
#pragma unroll
    for (int ni = 0; ni < 4; ++ni) {
#pragma unroll
      for (int reg = 0; reg < 4; ++reg) {
        int row = bx * 256 + wr * 128 + mi * 16 + (lane >> 4) * 4 + reg;
        int col = by * 128 + wc * 64 + ni * 16 + (lane & 15);
        if (col >= cols || row >= MR) continue;
        float v = acc[mi][ni][reg];
        if (row < NN) C1[(size_t)row * cols + col] = v;
        else C2[(size_t)(row - NN) * cols + col] = v;
      }
    }
  }
}

// ---- xb[n*CB + bb] = src[((b0+bb)*TT + t)*NN + n] (tight path) ----
__global__ void kx(const float* __restrict__ src, float* __restrict__ xb,
                   int t, int b0, int CB) {
  int i = blockIdx.x * 256 + threadIdx.x;
  if (i >= NN * CB) return;
  int bb = i % CB;
  int n = i / CB;
  xb[i] = fin(src[((size_t)(b0 + bb) * TT + t) * NN + n]);
}

// ---- batched: xa[n*(TT*CB) + t*CB + bb] = src[((b0+bb)*TT + t)*NN + n] ----
__global__ void kxa(const float* __restrict__ src, float* __restrict__ xa,
                    int b0, int CB) {
  int i = blockIdx.x * 256 + threadIdx.x;
  if (i >= NN * TT * CB) return;
  int bb = i % CB;
  int t = (i / CB) % TT;
  int n = i / (CB * TT);
  xa[i] = fin(src[((size_t)(b0 + bb) * TT + t) * NN + n]);
}

// ---- zb[i] *= h[i] ----
__global__ void kmulz(float* __restrict__ zb, const float* __restrict__ h, int n) {
  int i = blockIdx.x * 256 + threadIdx.x;
  if (i < n) zb[i] = zb[i] * h[i];
}

// ---- precompute per-node combined weights W[n,k,c,o] = sum_d E[n,d]*wp[d,k,c,o].
// Same d-loop order and fin() as the kgc recompute path -> bit-identical values.
__global__ __launch_bounds__(256) void kwc(const float* __restrict__ E,
                                           const float* __restrict__ wp,
                                           int Ctot, int O, float* __restrict__ W) {
  __shared__ float esm[DD];
  int n = blockIdx.x;
  int tid = threadIdx.x;
  if (tid < DD) esm[tid] = fin(E[n * DD + tid]);
  __syncthreads();
  int total = 3 * Ctot * O;
  for (int i = tid; i < total; i += 256) {
    int o = i % O;
    int rc = i / O;              // k*Ctot + crow
    int k = rc / Ctot;
    int crow = rc - k * Ctot;
    float wa = 0.f;
#pragma unroll
    for (int d = 0; d < DD; ++d)
      wa += esm[d] * fin(wp[((size_t)(d * 3 + k) * Ctot + crow) * O + o]);
    W[((size_t)(n * 3 + k) * Ctot + crow) * O + o] = wa;
  }
}

// ---- gconv; ldn = per-node row stride (elements) of x0/x1/x2.
// pW (optional): precomputed combined weights [n][k][Ctot][O]; when non-null
// the per-chunk ws tile is a coalesced load instead of a DD-contraction.
template <int O, int CB>
__global__ __launch_bounds__(256) void kgc(
    const float* __restrict__ x0, const float* __restrict__ x1, const float* __restrict__ x2,
    const float* __restrict__ wp, const float* __restrict__ pW,
    int Ctot, int base_c, int nC, int ldn,
    const float* __restrict__ E, const float* __restrict__ bp,
    int act, int accum, float* outA, float* outB,
    int update, const float* __restrict__ rb, float* hio) {
  __shared__ float xs[8][CB + 1];
  __shared__ float ws[8][O];
  __shared__ float esm[DD];
  int n = blockIdx.x;
  int tid = threadIdx.x;
  int to = tid % 16;
  int tb = tid / 16;
  if (tid < DD) esm[tid] = fin(E[n * DD + tid]);
  __syncthreads();
  constexpr int NO = O / 16;
  constexpr int NB = CB / 16;
  float acc[NB][NO];
#pragma unroll
  for (int i = 0; i < NB; ++i)
#pragma unroll
    for (int j = 0; j < NO; ++j) acc[i][j] = 0.f;
  const size_t nb = (size_t)n * CB;
  const size_t nx = (size_t)n * ldn;
  for (int k = 0; k < 3; ++k) {
    const float* xk = (k == 0) ? x0 : (k == 1) ? x1 : x2;
    for (int c0 = 0; c0 < nC; c0 += 8) {
      int chunk = (nC - c0 < 8) ? (nC - c0) : 8;
      for (int i = tid; i < chunk * CB; i += 256) {
        int cc = i % chunk;
        int b = i / chunk;
        xs[cc][b] = xk[nx + (size_t)b * nC + c0 + cc];
      }
      if (pW) {
        const float* wrow = pW + ((size_t)(n * 3 + k) * Ctot + base_c + c0) * O;
        for (int i = tid; i < chunk * O; i += 256) {
          int o = i % O;
          int cc = i / O;
          ws[cc][o] = wrow[(size_t)cc * O + o];
        }
      } else {
        for (int i = tid; i < chunk * O; i += 256) {
          int o = i % O;
          int cc = i / O;
          int crow = base_c + c0 + cc;
          float wa = 0.f;
#pragma unroll
          for (int d = 0; d < DD; ++d)
            wa += esm[d] * fin(wp[((size_t)(d * 3 + k) * Ctot + crow) * O + o]);
          ws[cc][o] = wa;
        }
      }
      __syncthreads();
      for (int cc = 0; cc < chunk; ++cc) {
        float xv[NB];
#pragma unroll
        for (int i = 0; i < NB; ++i) xv[i] = xs[cc][tb + 16 * i];
#pragma unroll
        for (int j = 0; j < NO; ++j) {
          float wv = ws[cc][to + 16 * j];
#pragma unroll
          for (int i = 0; i < NB; ++i) acc[i][j] += xv[i] * wv;
        }
      }
      __syncthreads();
    }
  }
#pragma unroll
  for (int i2 = 0; i2 < NB; ++i2) {
    int b = tb + 16 * i2;
#pragma unroll
    for (int j = 0; j < NO; ++j) {
      int o = to + 16 * j;
      float r = acc[i2][j];
      float* dst = (o < HH || !outB) ? (outA + (nb + b) * HH + (o % HH))
                                     : (outB + (nb + b) * HH + (o - HH));
      if (accum) r += *dst;
      if (bp) {
        float ba = 0.f;
#pragma unroll
        for (int d = 0; d < DD; ++d) ba += esm[d] * fin(bp[d * O + o]);
        r += ba;
      }
      r = fin(r);
      if (act == 1) r = sigmoid_safe(r);
      else if (act == 2) r = tanh_safe(r);
      if (update) {
        float rg = rb[(nb + b) * HH + o];
        float hold = hio[(nb + b) * HH + o];
        hio[(nb + b) * HH + o] = rg * hold + (1.f - rg) * r;
      } else {
        *dst = r;
      }
    }
  }
}

// ---- out[(b0+bb), o, n] = sum_h h1[n,bb,h]*cw[o*H+h] + cb[o] ----
__global__ void kfin(const float* __restrict__ h1, const float* __restrict__ cw,
                     const float* __restrict__ cb, float* __restrict__ out,
                     int b0, int CB) {
  int idx = blockIdx.x * 256 + threadIdx.x;
  if (idx >= CB * TT * NN) return;
  int n = idx % NN;
  int o = (idx / NN) % TT;
  int bb = idx / (NN * TT);
  const float* hp = h1 + ((size_t)n * CB + bb) * HH;
  float acc = fin(cb[o]);
#pragma unroll
  for (int hh = 0; hh < HH; ++hh) acc += hp[hh] * fin(cw[o * HH + hh]);
  out[((size_t)(b0 + bb) * TT + o) * NN + n] = fin(acc);
}

// Scheduling notes:
//  * h0 is mutated only at the end of layer 0; layer-1's chain(h0) at time t
//    equals layer-0's chain(h0) at time t+1 -> cache P1c/P2c (roomy mode).
//  * t=0: h0=h1=0 and zb=z*h=0 after kmulz -> those chains are exactly zero;
//    pass the zero state buffers as the support operands (bit-identical).
//  * roomy mode batches the 12 per-t x projections into one cols=TT*CB kmm.
//  * pg0/pu0/pg1/pu1: optional precomputed combined weights (null = recompute).
template <int CB>
static void run_chunks(const float* src, const float* E,
                       const float* gwp0, const float* gbp0,
                       const float* uwp0, const float* ubp0,
                       const float* gwp1, const float* gbp1,
                       const float* uwp1, const float* ubp1,
                       const float* cw, const float* cb,
                       float* out, f16* Mh, f16* Ml,
                       const float* pg0, const float* pu0,
                       const float* pg1, const float* pu1,
                       char* wsp, size_t off0, bool roomy, hipStream_t stream) {
  size_t off = off0;
  auto allocf = [&](size_t nelem) {
    float* p = (float*)(wsp + off);
    off += (nelem * 4 + 255) & ~(size_t)255;
    return p;
  };
  auto alloch = [&](size_t nelem) {
    f16* p = (f16*)(wsp + off);
    off += (nelem * 2 + 255) & ~(size_t)255;
    return p;
  };
  const int C = CB * HH;
  const int XC = TT * CB;
  const size_t NC = (size_t)NN * C;
  float* P1  = allocf(NC);
  float* P2  = allocf(NC);
  float* h0  = allocf(NC);
  float* h1  = allocf(NC);
  float* zb  = allocf(NC);
  float* rbf = allocf(NC);
  float* hc  = allocf(NC);
  f16* vh = alloch(NC);
  f16* vl = alloch(NC);
  float *P1c = nullptr, *P2c = nullptr;
  float *xa = nullptr, *xb1a = nullptr, *xb2a = nullptr;
  float *xb0 = nullptr, *xb1 = nullptr, *xb2 = nullptr;
  f16 *xth, *xtl;
  if (roomy) {
    P1c = allocf(NC);
    P2c = allocf(NC);
    xa   = allocf((size_t)NN * XC);
    xb1a = allocf((size_t)NN * XC);
    xb2a = allocf((size_t)NN * XC);
    xth = alloch((size_t)NN * XC);
    xtl = alloch((size_t)NN * XC);
  } else {
    xb0 = allocf((size_t)NN * CB);
    xb1 = allocf((size_t)NN * CB);
    xb2 = allocf((size_t)NN * CB);
    xth = alloch((size_t)NN * CB);
    xtl = alloch((size_t)NN * CB);
  }

  const int EW = (int)((NC + 255) / 256);
  const dim3 gConv((NN + 31) / 32, (C + 31) / 32);
  const dim3 gMM((MR + 255) / 256, (C + 127) / 128);
  float* nul = nullptr;

  auto chain_to = [&](const float* V, float* D1, float* D2) {
    kconvT<<<gConv, 256, 0, stream>>>(V, vh, vl, C);
    kmm<<<gMM, 256, 0, stream>>>(Mh, Ml, vh, vl, D1, D2, C);
  };

  for (int b0 = 0; b0 < BB; b0 += CB) {
    kzero<<<EW, 256, 0, stream>>>(h0, (int)NC);
    kzero<<<EW, 256, 0, stream>>>(h1, (int)NC);
    if (roomy) {
      kxa<<<((NN * XC) + 255) / 256, 256, 0, stream>>>(src, xa, b0, CB);
      dim3 gcx((NN + 31) / 32, (XC + 31) / 32);
      kconvT<<<gcx, 256, 0, stream>>>(xa, xth, xtl, XC);
      dim3 gmx((MR + 255) / 256, (XC + 127) / 128);
      kmm<<<gmx, 256, 0, stream>>>(Mh, Ml, xth, xtl, xb1a, xb2a, XC);
    }
    for (int t = 0; t < TT; ++t) {
      const bool tz = (t == 0);
      const float *xt0, *xt1, *xt2;
      int xln;
      if (roomy) {
        xt0 = xa + t * CB;
        xt1 = xb1a + t * CB;
        xt2 = xb2a + t * CB;
        xln = XC;
      } else {
        kx<<<(NN * CB + 255) / 256, 256, 0, stream>>>(src, xb0, t, b0, CB);
        dim3 gcx((NN + 31) / 32, (CB + 31) / 32);
        kconvT<<<gcx, 256, 0, stream>>>(xb0, xth, xtl, CB);
        dim3 gmx((MR + 255) / 256, (CB + 127) / 128);
        kmm<<<gmx, 256, 0, stream>>>(Mh, Ml, xth, xtl, xb1, xb2, CB);
        xt0 = xb0; xt1 = xb1; xt2 = xb2;
        xln = CB;
      }
      // ===== layer 0 (Ctot=65) =====
      const float *g1, *g2;
      if (tz) { g1 = h0; g2 = h0; }                 // h0 == 0: chains are zero
      else if (roomy) { g1 = P1c; g2 = P2c; }        // cached from prev t layer1
      else { chain_to(h0, P1, P2); g1 = P1; g2 = P2; }
      kgc<128, CB><<<NN, 256, 0, stream>>>(h0, g1, g2, gwp0, pg0, 65, 1, 64, C, E, nullptr,
                                           0, 0, zb, rbf, 0, nul, nul);
      kgc<128, CB><<<NN, 256, 0, stream>>>(xt0, xt1, xt2, gwp0, pg0, 65, 0, 1, xln, E, gbp0,
                                           1, 1, zb, rbf, 0, nul, nul);
      kgc<64, CB><<<NN, 256, 0, stream>>>(xt0, xt1, xt2, uwp0, pu0, 65, 0, 1, xln, E, nullptr,
                                          0, 0, hc, nul, 0, nul, nul);
      kmulz<<<EW, 256, 0, stream>>>(zb, h0, (int)NC);
      if (tz) {  // zb = z*0 = 0
        kgc<64, CB><<<NN, 256, 0, stream>>>(zb, zb, zb, uwp0, pu0, 65, 1, 64, C, E, ubp0,
                                            2, 1, hc, nul, 1, rbf, h0);
      } else {
        chain_to(zb, P1, P2);
        kgc<64, CB><<<NN, 256, 0, stream>>>(zb, P1, P2, uwp0, pu0, 65, 1, 64, C, E, ubp0,
                                            2, 1, hc, nul, 1, rbf, h0);
      }
      // ===== layer 1 (x = h0 new, Ctot=128) =====
      if (tz) {  // h1 == 0
        kgc<128, CB><<<NN, 256, 0, stream>>>(h1, h1, h1, gwp1, pg1, 128, 64, 64, C, E, nullptr,
                                             0, 0, zb, rbf, 0, nul, nul);
      } else {
        chain_to(h1, P1, P2);
        kgc<128, CB><<<NN, 256, 0, stream>>>(h1, P1, P2, gwp1, pg1, 128, 64, 64, C, E, nullptr,
                                             0, 0, zb, rbf, 0, nul, nul);
      }
      float* q1 = roomy ? P1c : P1;   // cache for next timestep's layer 0
      float* q2 = roomy ? P2c : P2;
      chain_to(h0, q1, q2);
      kgc<128, CB><<<NN, 256, 0, stream>>>(h0, q1, q2, gwp1, pg1, 128, 0, 64, C, E, gbp1,
                                           1, 1, zb, rbf, 0, nul, nul);
      kgc<64, CB><<<NN, 256, 0, stream>>>(h0, q1, q2, uwp1, pu1, 128, 0, 64, C, E, nullptr,
                                          0, 0, hc, nul, 0, nul, nul);
      kmulz<<<EW, 256, 0, stream>>>(zb, h1, (int)NC);
      if (tz) {  // zb = z*0 = 0
        kgc<64, CB><<<NN, 256, 0, stream>>>(zb, zb, zb, uwp1, pu1, 128, 64, 64, C, E, ubp1,
                                            2, 1, hc, nul, 1, rbf, h1);
      } else {
        chain_to(zb, P1, P2);
        kgc<64, CB><<<NN, 256, 0, stream>>>(zb, P1, P2, uwp1, pu1, 128, 64, 64, C, E, ubp1,
                                            2, 1, hc, nul, 1, rbf, h1);
      }
    }
    kfin<<<(CB * TT * NN + 255) / 256, 256, 0, stream>>>(h1, cw, cb, out, b0, CB);
  }
}

extern "C" void kernel_launch(void* const* d_in, const int* in_sizes, int n_in,
                              void* d_out, int out_size, void* d_ws, size_t ws_size,
                              hipStream_t stream) {
  const float* src  = (const float*)d_in[0];
  const float* E    = (const float*)d_in[1];
  const float* gwp0 = (const float*)d_in[2];
  const float* gbp0 = (const float*)d_in[3];
  const float* uwp0 = (const float*)d_in[4];
  const float* ubp0 = (const float*)d_in[5];
  const float* gwp1 = (const float*)d_in[6];
  const float* gbp1 = (const float*)d_in[7];
  const float* uwp1 = (const float*)d_in[8];
  const float* ubp1 = (const float*)d_in[9];
  const float* cw   = (const float*)d_in[10];
  const float* cb   = (const float*)d_in[11];
  float* out = (float*)d_out;
  (void)in_sizes; (void)n_in; (void)out_size;

  char* wsp = (char*)d_ws;
  size_t off = 0;
  f16* Mh = (f16*)(wsp + off); off += ((size_t)MR * NN * 2 + 255) & ~(size_t)255;
  f16* Ml = (f16*)(wsp + off); off += ((size_t)MR * NN * 2 + 255) & ~(size_t)255;

  // Optional precomputed combined-weight tensors (time-invariant, launch-lifetime).
  const size_t szg1 = (size_t)NN * 3 * 128 * 128;  // floats
  const size_t szu1 = (size_t)NN * 3 * 128 * 64;
  const size_t szg0 = (size_t)NN * 3 * 65 * 128;
  const size_t szu0 = (size_t)NN * 3 * 65 * 64;
  float *pg0 = nullptr, *pu0 = nullptr, *pg1 = nullptr, *pu1 = nullptr;
  bool wantAll = ws_size >= (size_t)1350 * 1000 * 1000;
  bool wantL1  = ws_size >= (size_t)1030 * 1000 * 1000;
  if (wantAll || wantL1) {
    pg1 = (float*)(wsp + off); off += (szg1 * 4 + 255) & ~(size_t)255;
    pu1 = (float*)(wsp + off); off += (szu1 * 4 + 255) & ~(size_t)255;
    if (wantAll) {
      pg0 = (float*)(wsp + off); off += (szg0 * 4 + 255) & ~(size_t)255;
      pu0 = (float*)(wsp + off); off += (szu0 * 4 + 255) & ~(size_t)255;
    }
  }
  size_t off0 = off;  // chunk area starts here
  // transient prologue buffers overlap the chunk area (dead before chunks start)
  float* A  = (float*)(wsp + off0);
  float* A2 = (float*)(wsp + off0 + (((size_t)NN * NN * 4 + 255) & ~(size_t)255));

  ka<<<NN, 256, 0, stream>>>(E, A);
  {
    dim3 g((NN + TM - 1) / TM, (NN + TM - 1) / TM);
    kg<<<g, 256, 0, stream>>>(A, A, A2, NN);
  }
  ksplitM<<<(MR * NN + 255) / 256, 256, 0, stream>>>(A, A2, Mh, Ml);
  if (pg1) {
    kwc<<<NN, 256, 0, stream>>>(E, gwp1, 128, 128, pg1);
    kwc<<<NN, 256, 0, stream>>>(E, uwp1, 128, 64, pu1);
  }
  if (pg0) {
    kwc<<<NN, 256, 0, stream>>>(E, gwp0, 65, 128, pg0);
    kwc<<<NN, 256, 0, stream>>>(E, uwp0, 65, 64, pu0);
  }

  // footprints past off0 (chunk area): CB=64 roomy ~353MB, tight ~265MB;
  // CB=32 roomy ~177MB, tight ~133MB; CB=16 roomy ~90MB, tight ~67MB.
  size_t rem = ws_size > off0 ? ws_size - off0 : 0;
  if (rem >= (size_t)368 * 1000 * 1000) {
    run_chunks<64>(src, E, gwp0, gbp0, uwp0, ubp0, gwp1, gbp1, uwp1, ubp1,
                   cw, cb, out, Mh, Ml, pg0, pu0, pg1, pu1, wsp, off0, true, stream);
  } else if (rem >= (size_t)288 * 1000 * 1000) {
    run_chunks<64>(src, E, gwp0, gbp0, uwp0, ubp0, gwp1, gbp1, uwp1, ubp1,
                   cw, cb, out, Mh, Ml, pg0, pu0, pg1, pu1, wsp, off0, false, stream);
  } else if (rem >= (size_t)193 * 1000 * 1000) {
    run_chunks<32>(src, E, gwp0, gbp0, uwp0, ubp0, gwp1, gbp1, uwp1, ubp1,
                   cw, cb, out, Mh, Ml, pg0, pu0, pg1, pu1, wsp, off0, true, stream);
  } else if (rem >= (size_t)153 * 1000 * 1000) {
    run_chunks<32>(src, E, gwp0, gbp0, uwp0, ubp0, gwp1, gbp1, uwp1, ubp1,
                   cw, cb, out, Mh, Ml, pg0, pu0, pg1, pu1, wsp, off0, false, stream);
  } else if (rem >= (size_t)98 * 1000 * 1000) {
    run_chunks<16>(src, E, gwp0, gbp0, uwp0, ubp0, gwp1, gbp1, uwp1, ubp1,
                   cw, cb, out, Mh, Ml, pg0, pu0, pg1, pu1, wsp, off0, true, stream);
  } else {
    run_chunks<16>(src, E, gwp0, gbp0, uwp0, ubp0, gwp1, gbp1, uwp1, ubp1,
                   cw, cb, out, Mh, Ml, pg0, pu0, pg1, pu1, wsp, off0, false, stream);
  }
}

// Round 7
// 53872.498 us; speedup vs baseline: 1.6948x; 1.6948x over previous
//
#include <hip/hip_runtime.h>
#include <hip/hip_bf16.h>
#include <math.h>

#define NN 2000
#define DD 16
#define BB 64
#define TT 12
#define HH 64
#define MR 4000   // rows of stacked M = [A ; 2A^2 - I]
#define SCL 2048.0f
#define ISCL (1.0f / 2048.0f)

typedef _Float16 f16;
typedef __attribute__((ext_vector_type(8))) _Float16 frag8h;  // 8 f16 = 4 VGPRs
typedef __attribute__((ext_vector_type(4))) float floatx4;

__device__ inline float fin(float v) {
  return (v == v && v > -1e30f && v < 1e30f) ? v : 0.f;
}
__device__ inline float sigmoid_safe(float x) {
  float e = expf(-fabsf(x));
  float s = 1.f / (1.f + e);
  return x >= 0.f ? s : 1.f - s;
}
__device__ inline float tanh_safe(float x) {
  float e = expf(-2.f * fabsf(x));
  float r = (1.f - e) / (1.f + e);
  return x >= 0.f ? r : -r;
}
// split v = hi + lo/2048, hi/lo f16
__device__ inline void split16(float v, f16& hi, f16& lo) {
  hi = (f16)v;
  lo = (f16)((v - (float)hi) * SCL);
}
// async global->LDS 16B: lands at (wave-uniform) l + lane*16
__device__ inline void gll16(const void* g, void* l) {
  __builtin_amdgcn_global_load_lds((const __attribute__((address_space(1))) void*)g,
                                   (__attribute__((address_space(3))) void*)l, 16, 0, 0);
}

__global__ void kzero(float* p, int n) {
  int i = blockIdx.x * 256 + threadIdx.x;
  if (i < n) p[i] = 0.f;
}

// ---- A = softmax(relu(E E^T), axis=1); all f32 ----
__global__ __launch_bounds__(256) void ka(const float* __restrict__ E,
                                          float* __restrict__ A) {
  __shared__ float s[NN];
  __shared__ float red[256];
  int n = blockIdx.x;
  float en[DD];
#pragma unroll
  for (int d = 0; d < DD; ++d) en[d] = fin(E[n * DD + d]);
  float lmax = 0.f;
  for (int m = threadIdx.x; m < NN; m += 256) {
    float acc = 0.f;
#pragma unroll
    for (int d = 0; d < DD; ++d) acc += en[d] * fin(E[m * DD + d]);
    acc = fmaxf(acc, 0.f);
    s[m] = acc;
    lmax = fmaxf(lmax, acc);
  }
  red[threadIdx.x] = lmax;
  __syncthreads();
  for (int w = 128; w > 0; w >>= 1) {
    if (threadIdx.x < w) red[threadIdx.x] = fmaxf(red[threadIdx.x], red[threadIdx.x + w]);
    __syncthreads();
  }
  float mx = red[0];
  __syncthreads();
  float lsum = 0.f;
  for (int m = threadIdx.x; m < NN; m += 256) {
    float e = expf(s[m] - mx);
    s[m] = e;
    lsum += e;
  }
  red[threadIdx.x] = lsum;
  __syncthreads();
  for (int w = 128; w > 0; w >>= 1) {
    if (threadIdx.x < w) red[threadIdx.x] += red[threadIdx.x + w];
    __syncthreads();
  }
  float inv = 1.f / red[0];
  for (int m = threadIdx.x; m < NN; m += 256) A[(size_t)n * NN + m] = s[m] * inv;
}

// ---- C(NN x cols) = A @ V ; f32, 64x64 tile (prologue only, for A^2) ----
#define TM 64
#define TK 32
__global__ __launch_bounds__(256) void kg(const float* __restrict__ A,
                                          const float* __restrict__ V,
                                          float* __restrict__ C, int cols) {
  __shared__ float As[TK][TM + 1];
  __shared__ float Bs[TK][TM + 1];
  int r0 = blockIdx.x * TM;
  int c0 = blockIdx.y * TM;
  int tid = threadIdx.x;
  int tx = tid % 16;
  int ty = tid / 16;
  float acc[4][4];
#pragma unroll
  for (int i = 0; i < 4; ++i)
#pragma unroll
    for (int j = 0; j < 4; ++j) acc[i][j] = 0.f;
  for (int k0 = 0; k0 < NN; k0 += TK) {
    for (int i = tid; i < TM * TK; i += 256) {
      int rr = i / TK, kk = i % TK;
      int gr = r0 + rr, gk = k0 + kk;
      As[kk][rr] = (gr < NN && gk < NN) ? A[(size_t)gr * NN + gk] : 0.f;
    }
    for (int i = tid; i < TK * TM; i += 256) {
      int kk = i / TM, cc = i % TM;
      int gk = k0 + kk, gc = c0 + cc;
      Bs[kk][cc] = (gk < NN && gc < cols) ? V[(size_t)gk * cols + gc] : 0.f;
    }
    __syncthreads();
#pragma unroll 4
    for (int kk = 0; kk < TK; ++kk) {
      float a[4], b[4];
#pragma unroll
      for (int i = 0; i < 4; ++i) a[i] = As[kk][ty * 4 + i];
#pragma unroll
      for (int j = 0; j < 4; ++j) b[j] = Bs[kk][tx * 4 + j];
#pragma unroll
      for (int i = 0; i < 4; ++i)
#pragma unroll
        for (int j = 0; j < 4; ++j) acc[i][j] += a[i] * b[j];
    }
    __syncthreads();
  }
#pragma unroll
  for (int i = 0; i < 4; ++i) {
    int gr = r0 + ty * 4 + i;
    if (gr >= NN) continue;
#pragma unroll
    for (int j = 0; j < 4; ++j) {
      int gc = c0 + tx * 4 + j;
      if (gc < cols) C[(size_t)gr * cols + gc] = acc[i][j];
    }
  }
}

// ---- build split M = [A ; 2A^2 - I] as f16 hi + lo/2048 ----
__global__ void ksplitM(const float* __restrict__ A, const float* __restrict__ A2,
                        f16* __restrict__ Mh, f16* __restrict__ Ml) {
  int i = blockIdx.x * 256 + threadIdx.x;
  if (i >= MR * NN) return;
  int m = i / NN;
  int k = i % NN;
  float v;
  if (m < NN) v = A[(size_t)m * NN + k];
  else {
    int mm = m - NN;
    v = 2.f * A2[(size_t)mm * NN + k] - (mm == k ? 1.f : 0.f);
  }
  f16 hi, lo;
  split16(v, hi, lo);
  Mh[i] = hi;
  Ml[i] = lo;
}

// ---- split+transpose: V f32 [2000][cols] -> Th/Tl f16 [cols][2000] ----
__global__ __launch_bounds__(256) void kconvT(const float* __restrict__ V,
                                              f16* __restrict__ Th,
                                              f16* __restrict__ Tl, int cols) {
  __shared__ float sh[32][33];
  int k0 = blockIdx.x * 32;
  int c0 = blockIdx.y * 32;
  int tx = threadIdx.x % 32;
  int ty = threadIdx.x / 32;  // 0..7
#pragma unroll
  for (int i = 0; i < 4; ++i) {
    int r = k0 + ty + i * 8;
    int c = c0 + tx;
    sh[ty + i * 8][tx] = (r < NN && c < cols) ? V[(size_t)r * cols + c] : 0.f;
  }
  __syncthreads();
#pragma unroll
  for (int i = 0; i < 4; ++i) {
    int cc = c0 + ty + i * 8;
    int kk = k0 + tx;
    if (cc < cols && kk < NN) {
      f16 hi, lo;
      split16(sh[tx][ty + i * 8], hi, lo);
      Th[(size_t)cc * NN + kk] = hi;
      Tl[(size_t)cc * NN + kk] = lo;
    }
  }
}

// ---- MFMA GEMM: FROZEN at the best-measured config (54.50 ms, R0-output).
// 128x128 tile, 4 waves (2x2), per-wave 64x64, dual f32 accumulators,
// single-buffer LDS, __syncthreads per K-step, XCD bijective swizzle.
// Probe record: R1 counted-vmcnt dbuf = null; R3 128x256 1-block/CU = -35%;
// R4 single-acc 12w/CU = null; R5/R6 256x128 = -65% (VGPR spill). Do not
// touch this kernel again without per-dispatch counters.
#define KT 32
__global__ __launch_bounds__(256, 2) void kmm(const f16* __restrict__ Mh,
                                              const f16* __restrict__ Ml,
                                              const f16* __restrict__ Bh,
                                              const f16* __restrict__ Bl,
                                              float* __restrict__ C1,
                                              float* __restrict__ C2, int cols) {
  __shared__ __align__(16) f16 Ash[128 * KT];
  __shared__ __align__(16) f16 Asl[128 * KT];
  __shared__ __align__(16) f16 Bsh[128 * KT];
  __shared__ __align__(16) f16 Bsl[128 * KT];
  int tid = threadIdx.x;
  int lane = tid & 63;
  int wave = tid >> 6;
  int wr = wave >> 1;   // 0..1
  int wc = wave & 1;    // 0..1
  // XCD swizzle: bijective contiguous-chunk remap (m204) for B-panel L2 reuse.
  int gx = gridDim.x;
  int nwg = gx * gridDim.y;
  int wg = blockIdx.y * gx + blockIdx.x;
  int q = nwg >> 3, r = nwg & 7;
  int xcd = wg & 7, lid = wg >> 3;
  int swz = (xcd < r ? xcd * (q + 1) : r * (q + 1) + (xcd - r) * q) + lid;
  int bx = swz % gx;
  int by = swz / gx;
  floatx4 acc0[4][4], acc1[4][4];
#pragma unroll
  for (int i = 0; i < 4; ++i)
#pragma unroll
    for (int j = 0; j < 4; ++j) {
      acc0[i][j] = (floatx4){0.f, 0.f, 0.f, 0.f};
      acc1[i][j] = (floatx4){0.f, 0.f, 0.f, 0.f};
    }
  const frag8h zf = {0, 0, 0, 0, 0, 0, 0, 0};

  auto comp = [&]() {
    frag8h ah[4], al[4], bh[4], bl[4];
#pragma unroll
    for (int mi = 0; mi < 4; ++mi) {
      int jr = wr * 4 + mi;                       // region index (16 rows each)
      ah[mi] = *(const frag8h*)(&Ash[jr * 512 + lane * 8]);
      al[mi] = *(const frag8h*)(&Asl[jr * 512 + lane * 8]);
    }
#pragma unroll
    for (int ni = 0; ni < 4; ++ni) {
      int jc = wc * 4 + ni;
      bh[ni] = *(const frag8h*)(&Bsh[jc * 512 + lane * 8]);
      bl[ni] = *(const frag8h*)(&Bsl[jc * 512 + lane * 8]);
    }
#pragma unroll
    for (int mi = 0; mi < 4; ++mi)
#pragma unroll
      for (int ni = 0; ni < 4; ++ni) {
        acc0[mi][ni] = __builtin_amdgcn_mfma_f32_16x16x32_f16(ah[mi], bh[ni], acc0[mi][ni], 0, 0, 0);
        acc1[mi][ni] = __builtin_amdgcn_mfma_f32_16x16x32_f16(ah[mi], bl[ni], acc1[mi][ni], 0, 0, 0);
        acc1[mi][ni] = __builtin_amdgcn_mfma_f32_16x16x32_f16(al[mi], bh[ni], acc1[mi][ni], 0, 0, 0);
      }
  };

  const int lr = lane & 15;   // row within region this lane stages
  const int lq = lane >> 4;   // k-chunk this lane stages
  // fast path: full 32-k tiles via global_load_lds
  for (int k0 = 0; k0 + KT <= NN; k0 += KT) {
#pragma unroll
    for (int jj = 0; jj < 2; ++jj) {
      int j = wave * 2 + jj;            // region 0..7
      int r2 = j * 16 + lr;
      size_t ko = (size_t)k0 + lq * 8;
      int gra = bx * 128 + r2;
      if (gra < MR) {
        gll16(Mh + (size_t)gra * NN + ko, Ash + j * 512);
        gll16(Ml + (size_t)gra * NN + ko, Asl + j * 512);
      }
      int grb = by * 128 + r2;
      if (grb < cols) {
        gll16(Bh + (size_t)grb * NN + ko, Bsh + j * 512);
        gll16(Bl + (size_t)grb * NN + ko, Bsl + j * 512);
      }
    }
    __syncthreads();
    comp();
    __syncthreads();
  }
  // tail (k0 = 1984, 16 valid k): guarded VGPR staging, same slot layout
  {
    int k0 = (NN / KT) * KT;
    if (k0 < NN) {
      for (int c = tid; c < 512; c += 256) {
        int j = c >> 6;          // region
        int ll = c & 63;         // slot within region
        int qq = ll >> 4;
        int rr = ll & 15;
        int r2 = j * 16 + rr;
        int gk = k0 + qq * 8;
        bool kok = (gk + 8 <= NN);
        int gra = bx * 128 + r2;
        bool aok = kok && (gra < MR);
        size_t ga = (size_t)gra * NN + gk;
        *(frag8h*)(&Ash[c * 8]) = aok ? *(const frag8h*)(Mh + ga) : zf;
        *(frag8h*)(&Asl[c * 8]) = aok ? *(const frag8h*)(Ml + ga) : zf;
        int grb = by * 128 + r2;
        bool bok = kok && (grb < cols);
        size_t gb = (size_t)grb * NN + gk;
        *(frag8h*)(&Bsh[c * 8]) = bok ? *(const frag8h*)(Bh + gb) : zf;
        *(frag8h*)(&Bsl[c * 8]) = bok ? *(const frag8h*)(Bl + gb) : zf;
      }
      __syncthreads();
      comp();
      __syncthreads();
    }
  }
  // store: C/D layout col = lane&15, row = (lane>>4)*4 + reg
#pragma unroll
  for (int mi = 0; mi < 4; ++mi) {
#pragma unroll
    for (int ni = 0; ni < 4; ++ni) {
#pragma unroll
      for (int reg = 0; reg < 4; ++reg) {
        int row = bx * 128 + wr * 64 + mi * 16 + (lane >> 4) * 4 + reg;
        int col = by * 128 + wc * 64 + ni * 16 + (lane & 15);
        if (col >= cols || row >= MR) continue;
        float v = acc0[mi][ni][reg] + acc1[mi][ni][reg] * ISCL;
        if (row < NN) C1[(size_t)row * cols + col] = v;
        else C2[(size_t)(row - NN) * cols + col] = v;
      }
    }
  }
}

// ---- xb[n*CB + bb] = src[((b0+bb)*TT + t)*NN + n] (tight path) ----
__global__ void kx(const float* __restrict__ src, float* __restrict__ xb,
                   int t, int b0, int CB) {
  int i = blockIdx.x * 256 + threadIdx.x;
  if (i >= NN * CB) return;
  int bb = i % CB;
  int n = i / CB;
  xb[i] = fin(src[((size_t)(b0 + bb) * TT + t) * NN + n]);
}

// ---- batched: xa[n*(TT*CB) + t*CB + bb] = src[((b0+bb)*TT + t)*NN + n] ----
__global__ void kxa(const float* __restrict__ src, float* __restrict__ xa,
                    int b0, int CB) {
  int i = blockIdx.x * 256 + threadIdx.x;
  if (i >= NN * TT * CB) return;
  int bb = i % CB;
  int t = (i / CB) % TT;
  int n = i / (CB * TT);
  xa[i] = fin(src[((size_t)(b0 + bb) * TT + t) * NN + n]);
}

// ---- zb[i] *= h[i] ----
__global__ void kmulz(float* __restrict__ zb, const float* __restrict__ h, int n) {
  int i = blockIdx.x * 256 + threadIdx.x;
  if (i < n) zb[i] = zb[i] * h[i];
}

// ---- precompute per-node combined weights W[n,k,c,o] = sum_d E[n,d]*wp[d,k,c,o].
__global__ __launch_bounds__(256) void kwc(const float* __restrict__ E,
                                           const float* __restrict__ wp,
                                           int Ctot, int O, float* __restrict__ W) {
  __shared__ float esm[DD];
  int n = blockIdx.x;
  int tid = threadIdx.x;
  if (tid < DD) esm[tid] = fin(E[n * DD + tid]);
  __syncthreads();
  int total = 3 * Ctot * O;
  for (int i = tid; i < total; i += 256) {
    int o = i % O;
    int rc = i / O;              // k*Ctot + crow
    int k = rc / Ctot;
    int crow = rc - k * Ctot;
    float wa = 0.f;
#pragma unroll
    for (int d = 0; d < DD; ++d)
      wa += esm[d] * fin(wp[((size_t)(d * 3 + k) * Ctot + crow) * O + o]);
    W[((size_t)(n * 3 + k) * Ctot + crow) * O + o] = wa;
  }
}

// ---- gconv (chunk=16: fewer barriers; accumulation order over channels
// unchanged -> bit-identical results). ldn = per-node row stride of x.
template <int O, int CB>
__global__ __launch_bounds__(256) void kgc(
    const float* __restrict__ x0, const float* __restrict__ x1, const float* __restrict__ x2,
    const float* __restrict__ wp, const float* __restrict__ pW,
    int Ctot, int base_c, int nC, int ldn,
    const float* __restrict__ E, const float* __restrict__ bp,
    int act, int accum, float* outA, float* outB,
    int update, const float* __restrict__ rb, float* hio) {
  __shared__ float xs[16][CB + 1];
  __shared__ float ws[16][O];
  __shared__ float esm[DD];
  int n = blockIdx.x;
  int tid = threadIdx.x;
  int to = tid % 16;
  int tb = tid / 16;
  if (tid < DD) esm[tid] = fin(E[n * DD + tid]);
  __syncthreads();
  constexpr int NO = O / 16;
  constexpr int NB = CB / 16;
  float acc[NB][NO];
#pragma unroll
  for (int i = 0; i < NB; ++i)
#pragma unroll
    for (int j = 0; j < NO; ++j) acc[i][j] = 0.f;
  const size_t nb = (size_t)n * CB;
  const size_t nx = (size_t)n * ldn;
  for (int k = 0; k < 3; ++k) {
    const float* xk = (k == 0) ? x0 : (k == 1) ? x1 : x2;
    for (int c0 = 0; c0 < nC; c0 += 16) {
      int chunk = (nC - c0 < 16) ? (nC - c0) : 16;
      for (int i = tid; i < chunk * CB; i += 256) {
        int cc = i % chunk;
        int b = i / chunk;
        xs[cc][b] = xk[nx + (size_t)b * nC + c0 + cc];
      }
      if (pW) {
        const float* wrow = pW + ((size_t)(n * 3 + k) * Ctot + base_c + c0) * O;
        for (int i = tid; i < chunk * O; i += 256) {
          int o = i % O;
          int cc = i / O;
          ws[cc][o] = wrow[(size_t)cc * O + o];
        }
      } else {
        for (int i = tid; i < chunk * O; i += 256) {
          int o = i % O;
          int cc = i / O;
          int crow = base_c + c0 + cc;
          float wa = 0.f;
#pragma unroll
          for (int d = 0; d < DD; ++d)
            wa += esm[d] * fin(wp[((size_t)(d * 3 + k) * Ctot + crow) * O + o]);
          ws[cc][o] = wa;
        }
      }
      __syncthreads();
      for (int cc = 0; cc < chunk; ++cc) {
        float xv[NB];
#pragma unroll
        for (int i = 0; i < NB; ++i) xv[i] = xs[cc][tb + 16 * i];
#pragma unroll
        for (int j = 0; j < NO; ++j) {
          float wv = ws[cc][to + 16 * j];
#pragma unroll
          for (int i = 0; i < NB; ++i) acc[i][j] += xv[i] * wv;
        }
      }
      __syncthreads();
    }
  }
#pragma unroll
  for (int i2 = 0; i2 < NB; ++i2) {
    int b = tb + 16 * i2;
#pragma unroll
    for (int j = 0; j < NO; ++j) {
      int o = to + 16 * j;
      float r = acc[i2][j];
      float* dst = (o < HH || !outB) ? (outA + (nb + b) * HH + (o % HH))
                                     : (outB + (nb + b) * HH + (o - HH));
      if (accum) r += *dst;
      if (bp) {
        float ba = 0.f;
#pragma unroll
        for (int d = 0; d < DD; ++d) ba += esm[d] * fin(bp[d * O + o]);
        r += ba;
      }
      r = fin(r);
      if (act == 1) r = sigmoid_safe(r);
      else if (act == 2) r = tanh_safe(r);
      if (update) {
        float rg = rb[(nb + b) * HH + o];
        float hold = hio[(nb + b) * HH + o];
        hio[(nb + b) * HH + o] = rg * hold + (1.f - rg) * r;
      } else {
        *dst = r;
      }
    }
  }
}

// ---- NEW fused kernel: gate(h-part) + gate(x-part) + update(x-part).
// Replaces 3 kgc launches and the zb/rbf HBM round-trip. Pass A accumulates
// the gate contribution of the A-inputs (h supports); pass B accumulates
// gate AND update contributions of the B-inputs sharing one xs tile.
// Epilogue: gate -> +bias, sigmoid -> zb/rbf ; update -> hc (raw fin).
template <int CB>
__global__ __launch_bounds__(256) void kgf(
    const float* __restrict__ A0, const float* __restrict__ A1, const float* __restrict__ A2,
    int nCA, int baseA, int ldA,
    const float* __restrict__ B0, const float* __restrict__ B1, const float* __restrict__ B2,
    int nCB, int baseB, int ldB,
    const float* __restrict__ wpg, const float* __restrict__ pWg,
    const float* __restrict__ bpg,
    const float* __restrict__ wpu, const float* __restrict__ pWu,
    int Ctot, const float* __restrict__ E,
    float* __restrict__ zb, float* __restrict__ rbf, float* __restrict__ hc) {
  __shared__ float xs[16][CB + 1];
  __shared__ float wsg[16][128];
  __shared__ float wsu[16][64];
  __shared__ float esm[DD];
  int n = blockIdx.x;
  int tid = threadIdx.x;
  int to = tid % 16;
  int tb = tid / 16;
  if (tid < DD) esm[tid] = fin(E[n * DD + tid]);
  __syncthreads();
  constexpr int NB = CB / 16;
  float accg[NB][8];
  float accu[NB][4];
#pragma unroll
  for (int i = 0; i < NB; ++i) {
#pragma unroll
    for (int j = 0; j < 8; ++j) accg[i][j] = 0.f;
#pragma unroll
    for (int j = 0; j < 4; ++j) accu[i][j] = 0.f;
  }
  const size_t nb = (size_t)n * CB;

  // ---- pass A: gate only ----
  {
    const size_t nx = (size_t)n * ldA;
    for (int k = 0; k < 3; ++k) {
      const float* xk = (k == 0) ? A0 : (k == 1) ? A1 : A2;
      for (int c0 = 0; c0 < nCA; c0 += 16) {
        int chunk = (nCA - c0 < 16) ? (nCA - c0) : 16;
        for (int i = tid; i < chunk * CB; i += 256) {
          int cc = i % chunk;
          int b = i / chunk;
          xs[cc][b] = xk[nx + (size_t)b * nCA + c0 + cc];
        }
        if (pWg) {
          const float* wrow = pWg + ((size_t)(n * 3 + k) * Ctot + baseA + c0) * 128;
          for (int i = tid; i < chunk * 128; i += 256) {
            int o = i % 128;
            int cc = i / 128;
            wsg[cc][o] = wrow[(size_t)cc * 128 + o];
          }
        } else {
          for (int i = tid; i < chunk * 128; i += 256) {
            int o = i % 128;
            int cc = i / 128;
            int crow = baseA + c0 + cc;
            float wa = 0.f;
#pragma unroll
            for (int d = 0; d < DD; ++d)
              wa += esm[d] * fin(wpg[((size_t)(d * 3 + k) * Ctot + crow) * 128 + o]);
            wsg[cc][o] = wa;
          }
        }
        __syncthreads();
        for (int cc = 0; cc < chunk; ++cc) {
          float xv[NB];
#pragma unroll
          for (int i = 0; i < NB; ++i) xv[i] = xs[cc][tb + 16 * i];
#pragma unroll
          for (int j = 0; j < 8; ++j) {
            float wv = wsg[cc][to + 16 * j];
#pragma unroll
            for (int i = 0; i < NB; ++i) accg[i][j] += xv[i] * wv;
          }
        }
        __syncthreads();
      }
    }
  }
  // ---- pass B: gate + update ----
  {
    const size_t nx = (size_t)n * ldB;
    for (int k = 0; k < 3; ++k) {
      const float* xk = (k == 0) ? B0 : (k == 1) ? B1 : B2;
      for (int c0 = 0; c0 < nCB; c0 += 16) {
        int chunk = (nCB - c0 < 16) ? (nCB - c0) : 16;
        for (int i = tid; i < chunk * CB; i += 256) {
          int cc = i % chunk;
          int b = i / chunk;
          xs[cc][b] = xk[nx + (size_t)b * nCB + c0 + cc];
        }
        if (pWg) {
          const float* wrow = pWg + ((size_t)(n * 3 + k) * Ctot + baseB + c0) * 128;
          for (int i = tid; i < chunk * 128; i += 256) {
            int o = i % 128;
            int cc = i / 128;
            wsg[cc][o] = wrow[(size_t)cc * 128 + o];
          }
        } else {
          for (int i = tid; i < chunk * 128; i += 256) {
            int o = i % 128;
            int cc = i / 128;
            int crow = baseB + c0 + cc;
            float wa = 0.f;
#pragma unroll
            for (int d = 0; d < DD; ++d)
              wa += esm[d] * fin(wpg[((size_t)(d * 3 + k) * Ctot + crow) * 128 + o]);
            wsg[cc][o] = wa;
          }
        }
        if (pWu) {
          const float* wrow = pWu + ((size_t)(n * 3 + k) * Ctot + baseB + c0) * 64;
          for (int i = tid; i < chunk * 64; i += 256) {
            int o = i % 64;
            int cc = i / 64;
            wsu[cc][o] = wrow[(size_t)cc * 64 + o];
          }
        } else {
          for (int i = tid; i < chunk * 64; i += 256) {
            int o = i % 64;
            int cc = i / 64;
            int crow = baseB + c0 + cc;
            float wa = 0.f;
#pragma unroll
            for (int d = 0; d < DD; ++d)
              wa += esm[d] * fin(wpu[((size_t)(d * 3 + k) * Ctot + crow) * 64 + o]);
            wsu[cc][o] = wa;
          }
        }
        __syncthreads();
        for (int cc = 0; cc < chunk; ++cc) {
          float xv[NB];
#pragma unroll
          for (int i = 0; i < NB; ++i) xv[i] = xs[cc][tb + 16 * i];
#pragma unroll
          for (int j = 0; j < 8; ++j) {
            float wv = wsg[cc][to + 16 * j];
#pragma unroll
            for (int i = 0; i < NB; ++i) accg[i][j] += xv[i] * wv;
          }
#pragma unroll
          for (int j = 0; j < 4; ++j) {
            float wv = wsu[cc][to + 16 * j];
#pragma unroll
            for (int i = 0; i < NB; ++i) accu[i][j] += xv[i] * wv;
          }
        }
        __syncthreads();
      }
    }
  }
  // ---- epilogue ----
#pragma unroll
  for (int i2 = 0; i2 < NB; ++i2) {
    int b = tb + 16 * i2;
#pragma unroll
    for (int j = 0; j < 8; ++j) {
      int o = to + 16 * j;
      float r = accg[i2][j];
      float ba = 0.f;
#pragma unroll
      for (int d = 0; d < DD; ++d) ba += esm[d] * fin(bpg[d * 128 + o]);
      r = fin(r + ba);
      r = sigmoid_safe(r);
      if (o < HH) zb[(nb + b) * HH + o] = r;
      else rbf[(nb + b) * HH + (o - HH)] = r;
    }
#pragma unroll
    for (int j = 0; j < 4; ++j) {
      int o = to + 16 * j;
      hc[(nb + b) * HH + o] = fin(accu[i2][j]);
    }
  }
}

// ---- out[(b0+bb), o, n] = sum_h h1[n,bb,h]*cw[o*H+h] + cb[o] ----
__global__ void kfin(const float* __restrict__ h1, const float* __restrict__ cw,
                     const float* __restrict__ cb, float* __restrict__ out,
                     int b0, int CB) {
  int idx = blockIdx.x * 256 + threadIdx.x;
  if (idx >= CB * TT * NN) return;
  int n = idx % NN;
  int o = (idx / NN) % TT;
  int bb = idx / (NN * TT);
  const float* hp = h1 + ((size_t)n * CB + bb) * HH;
  float acc = fin(cb[o]);
#pragma unroll
  for (int hh = 0; hh < HH; ++hh) acc += hp[hh] * fin(cw[o * HH + hh]);
  out[((size_t)(b0 + bb) * TT + o) * NN + n] = fin(acc);
}

// Scheduling notes:
//  * h0 is mutated only at the end of layer 0; layer-1's chain(h0) at time t
//    equals layer-0's chain(h0) at time t+1 -> cache P1c/P2c (roomy mode).
//  * t=0: h0=h1=0 and zb=z*h=0 after kmulz -> those chains are exactly zero;
//    pass the zero state buffers as the support operands.
//  * kgf fuses {gate-h, gate-x, update-x} per layer-timestep (roomy: both
//    layers; tight: layer 0 only, since layer 1 needs two live chains).
template <int CB>
static void run_chunks(const float* src, const float* E,
                       const float* gwp0, const float* gbp0,
                       const float* uwp0, const float* ubp0,
                       const float* gwp1, const float* gbp1,
                       const float* uwp1, const float* ubp1,
                       const float* cw, const float* cb,
                       float* out, f16* Mh, f16* Ml,
                       const float* pg0, const float* pu0,
                       const float* pg1, const float* pu1,
                       char* wsp, size_t off0, bool roomy, hipStream_t stream) {
  size_t off = off0;
  auto allocf = [&](size_t nelem) {
    float* p = (float*)(wsp + off);
    off += (nelem * 4 + 255) & ~(size_t)255;
    return p;
  };
  auto alloch = [&](size_t nelem) {
    f16* p = (f16*)(wsp + off);
    off += (nelem * 2 + 255) & ~(size_t)255;
    return p;
  };
  const int C = CB * HH;
  const int XC = TT * CB;
  const size_t NC = (size_t)NN * C;
  float* P1  = allocf(NC);
  float* P2  = allocf(NC);
  float* h0  = allocf(NC);
  float* h1  = allocf(NC);
  float* zb  = allocf(NC);
  float* rbf = allocf(NC);
  float* hc  = allocf(NC);
  f16* vh = alloch(NC);
  f16* vl = alloch(NC);
  float *P1c = nullptr, *P2c = nullptr;
  float *xa = nullptr, *xb1a = nullptr, *xb2a = nullptr;
  float *xb0 = nullptr, *xb1 = nullptr, *xb2 = nullptr;
  f16 *xth, *xtl;
  if (roomy) {
    P1c = allocf(NC);
    P2c = allocf(NC);
    xa   = allocf((size_t)NN * XC);
    xb1a = allocf((size_t)NN * XC);
    xb2a = allocf((size_t)NN * XC);
    xth = alloch((size_t)NN * XC);
    xtl = alloch((size_t)NN * XC);
  } else {
    xb0 = allocf((size_t)NN * CB);
    xb1 = allocf((size_t)NN * CB);
    xb2 = allocf((size_t)NN * CB);
    xth = alloch((size_t)NN * CB);
    xtl = alloch((size_t)NN * CB);
  }

  const int EW = (int)((NC + 255) / 256);
  const dim3 gConv((NN + 31) / 32, (C + 31) / 32);
  const dim3 gMM((MR + 127) / 128, (C + 127) / 128);
  float* nul = nullptr;

  auto chain_to = [&](const float* V, float* D1, float* D2) {
    kconvT<<<gConv, 256, 0, stream>>>(V, vh, vl, C);
    kmm<<<gMM, 256, 0, stream>>>(Mh, Ml, vh, vl, D1, D2, C);
  };

  for (int b0 = 0; b0 < BB; b0 += CB) {
    kzero<<<EW, 256, 0, stream>>>(h0, (int)NC);
    kzero<<<EW, 256, 0, stream>>>(h1, (int)NC);
    if (roomy) {
      kxa<<<((NN * XC) + 255) / 256, 256, 0, stream>>>(src, xa, b0, CB);
      dim3 gcx((NN + 31) / 32, (XC + 31) / 32);
      kconvT<<<gcx, 256, 0, stream>>>(xa, xth, xtl, XC);
      dim3 gmx((MR + 127) / 128, (XC + 127) / 128);
      kmm<<<gmx, 256, 0, stream>>>(Mh, Ml, xth, xtl, xb1a, xb2a, XC);
    }
    for (int t = 0; t < TT; ++t) {
      const bool tz = (t == 0);
      const float *xt0, *xt1, *xt2;
      int xln;
      if (roomy) {
        xt0 = xa + t * CB;
        xt1 = xb1a + t * CB;
        xt2 = xb2a + t * CB;
        xln = XC;
      } else {
        kx<<<(NN * CB + 255) / 256, 256, 0, stream>>>(src, xb0, t, b0, CB);
        dim3 gcx((NN + 31) / 32, (CB + 31) / 32);
        kconvT<<<gcx, 256, 0, stream>>>(xb0, xth, xtl, CB);
        dim3 gmx((MR + 127) / 128, (CB + 127) / 128);
        kmm<<<gmx, 256, 0, stream>>>(Mh, Ml, xth, xtl, xb1, xb2, CB);
        xt0 = xb0; xt1 = xb1; xt2 = xb2;
        xln = CB;
      }
      // ===== layer 0 (Ctot=65): fused gate+updateX =====
      const float *g1, *g2;
      if (tz) { g1 = h0; g2 = h0; }                 // h0 == 0: chains are zero
      else if (roomy) { g1 = P1c; g2 = P2c; }        // cached from prev t layer1
      else { chain_to(h0, P1, P2); g1 = P1; g2 = P2; }
      kgf<CB><<<NN, 256, 0, stream>>>(h0, g1, g2, 64, 1, C,
                                      xt0, xt1, xt2, 1, 0, xln,
                                      gwp0, pg0, gbp0, uwp0, pu0, 65, E,
                                      zb, rbf, hc);
      kmulz<<<EW, 256, 0, stream>>>(zb, h0, (int)NC);
      if (tz) {  // zb = z*0 = 0
        kgc<64, CB><<<NN, 256, 0, stream>>>(zb, zb, zb, uwp0, pu0, 65, 1, 64, C, E, ubp0,
                                            2, 1, hc, nul, 1, rbf, h0);
      } else {
        chain_to(zb, P1, P2);
        kgc<64, CB><<<NN, 256, 0, stream>>>(zb, P1, P2, uwp0, pu0, 65, 1, 64, C, E, ubp0,
                                            2, 1, hc, nul, 1, rbf, h0);
      }
      // ===== layer 1 (x = h0 new, Ctot=128) =====
      if (roomy) {
        const float *a1, *a2;
        if (tz) { a1 = h1; a2 = h1; }
        else { chain_to(h1, P1, P2); a1 = P1; a2 = P2; }
        chain_to(h0, P1c, P2c);   // also cached for next t layer 0
        kgf<CB><<<NN, 256, 0, stream>>>(h1, a1, a2, 64, 64, C,
                                        h0, P1c, P2c, 64, 0, C,
                                        gwp1, pg1, gbp1, uwp1, pu1, 128, E,
                                        zb, rbf, hc);
      } else {
        if (tz) {
          kgc<128, CB><<<NN, 256, 0, stream>>>(h1, h1, h1, gwp1, pg1, 128, 64, 64, C, E, nullptr,
                                               0, 0, zb, rbf, 0, nul, nul);
        } else {
          chain_to(h1, P1, P2);
          kgc<128, CB><<<NN, 256, 0, stream>>>(h1, P1, P2, gwp1, pg1, 128, 64, 64, C, E, nullptr,
                                               0, 0, zb, rbf, 0, nul, nul);
        }
        chain_to(h0, P1, P2);
        kgc<128, CB><<<NN, 256, 0, stream>>>(h0, P1, P2, gwp1, pg1, 128, 0, 64, C, E, gbp1,
                                             1, 1, zb, rbf, 0, nul, nul);
        kgc<64, CB><<<NN, 256, 0, stream>>>(h0, P1, P2, uwp1, pu1, 128, 0, 64, C, E, nullptr,
                                            0, 0, hc, nul, 0, nul, nul);
      }
      kmulz<<<EW, 256, 0, stream>>>(zb, h1, (int)NC);
      if (tz) {  // zb = z*0 = 0
        kgc<64, CB><<<NN, 256, 0, stream>>>(zb, zb, zb, uwp1, pu1, 128, 64, 64, C, E, ubp1,
                                            2, 1, hc, nul, 1, rbf, h1);
      } else {
        chain_to(zb, P1, P2);
        kgc<64, CB><<<NN, 256, 0, stream>>>(zb, P1, P2, uwp1, pu1, 128, 64, 64, C, E, ubp1,
                                            2, 1, hc, nul, 1, rbf, h1);
      }
    }
    kfin<<<(CB * TT * NN + 255) / 256, 256, 0, stream>>>(h1, cw, cb, out, b0, CB);
  }
}

extern "C" void kernel_launch(void* const* d_in, const int* in_sizes, int n_in,
                              void* d_out, int out_size, void* d_ws, size_t ws_size,
                              hipStream_t stream) {
  const float* src  = (const float*)d_in[0];
  const float* E    = (const float*)d_in[1];
  const float* gwp0 = (const float*)d_in[2];
  const float* gbp0 = (const float*)d_in[3];
  const float* uwp0 = (const float*)d_in[4];
  const float* ubp0 = (const float*)d_in[5];
  const float* gwp1 = (const float*)d_in[6];
  const float* gbp1 = (const float*)d_in[7];
  const float* uwp1 = (const float*)d_in[8];
  const float* ubp1 = (const float*)d_in[9];
  const float* cw   = (const float*)d_in[10];
  const float* cb   = (const float*)d_in[11];
  float* out = (float*)d_out;
  (void)in_sizes; (void)n_in; (void)out_size;

  char* wsp = (char*)d_ws;
  size_t off = 0;
  f16* Mh = (f16*)(wsp + off); off += ((size_t)MR * NN * 2 + 255) & ~(size_t)255;
  f16* Ml = (f16*)(wsp + off); off += ((size_t)MR * NN * 2 + 255) & ~(size_t)255;

  // Optional precomputed combined-weight tensors (time-invariant, launch-lifetime).
  const size_t szg1 = (size_t)NN * 3 * 128 * 128;  // floats
  const size_t szu1 = (size_t)NN * 3 * 128 * 64;
  const size_t szg0 = (size_t)NN * 3 * 65 * 128;
  const size_t szu0 = (size_t)NN * 3 * 65 * 64;
  float *pg0 = nullptr, *pu0 = nullptr, *pg1 = nullptr, *pu1 = nullptr;
  bool wantAll = ws_size >= (size_t)1350 * 1000 * 1000;
  bool wantL1  = ws_size >= (size_t)1030 * 1000 * 1000;
  if (wantAll || wantL1) {
    pg1 = (float*)(wsp + off); off += (szg1 * 4 + 255) & ~(size_t)255;
    pu1 = (float*)(wsp + off); off += (szu1 * 4 + 255) & ~(size_t)255;
    if (wantAll) {
      pg0 = (float*)(wsp + off); off += (szg0 * 4 + 255) & ~(size_t)255;
      pu0 = (float*)(wsp + off); off += (szu0 * 4 + 255) & ~(size_t)255;
    }
  }
  size_t off0 = off;  // chunk area starts here
  // transient prologue buffers overlap the chunk area (dead before chunks start)
  float* A  = (float*)(wsp + off0);
  float* A2 = (float*)(wsp + off0 + (((size_t)NN * NN * 4 + 255) & ~(size_t)255));

  ka<<<NN, 256, 0, stream>>>(E, A);
  {
    dim3 g((NN + TM - 1) / TM, (NN + TM - 1) / TM);
    kg<<<g, 256, 0, stream>>>(A, A, A2, NN);
  }
  ksplitM<<<(MR * NN + 255) / 256, 256, 0, stream>>>(A, A2, Mh, Ml);
  if (pg1) {
    kwc<<<NN, 256, 0, stream>>>(E, gwp1, 128, 128, pg1);
    kwc<<<NN, 256, 0, stream>>>(E, uwp1, 128, 64, pu1);
  }
  if (pg0) {
    kwc<<<NN, 256, 0, stream>>>(E, gwp0, 65, 128, pg0);
    kwc<<<NN, 256, 0, stream>>>(E, uwp0, 65, 64, pu0);
  }

  // footprints past off0 (chunk area): CB=64 roomy ~353MB, tight ~265MB;
  // CB=32 roomy ~177MB, tight ~133MB; CB=16 roomy ~90MB, tight ~67MB.
  size_t rem = ws_size > off0 ? ws_size - off0 : 0;
  if (rem >= (size_t)368 * 1000 * 1000) {
    run_chunks<64>(src, E, gwp0, gbp0, uwp0, ubp0, gwp1, gbp1, uwp1, ubp1,
                   cw, cb, out, Mh, Ml, pg0, pu0, pg1, pu1, wsp, off0, true, stream);
  } else if (rem >= (size_t)288 * 1000 * 1000) {
    run_chunks<64>(src, E, gwp0, gbp0, uwp0, ubp0, gwp1, gbp1, uwp1, ubp1,
                   cw, cb, out, Mh, Ml, pg0, pu0, pg1, pu1, wsp, off0, false, stream);
  } else if (rem >= (size_t)193 * 1000 * 1000) {
    run_chunks<32>(src, E, gwp0, gbp0, uwp0, ubp0, gwp1, gbp1, uwp1, ubp1,
                   cw, cb, out, Mh, Ml, pg0, pu0, pg1, pu1, wsp, off0, true, stream);
  } else if (rem >= (size_t)153 * 1000 * 1000) {
    run_chunks<32>(src, E, gwp0, gbp0, uwp0, ubp0, gwp1, gbp1, uwp1, ubp1,
                   cw, cb, out, Mh, Ml, pg0, pu0, pg1, pu1, wsp, off0, false, stream);
  } else if (rem >= (size_t)98 * 1000 * 1000) {
    run_chunks<16>(src, E, gwp0, gbp0, uwp0, ubp0, gwp1, gbp1, uwp1, ubp1,
                   cw, cb, out, Mh, Ml, pg0, pu0, pg1, pu1, wsp, off0, true, stream);
  } else {
    run_chunks<16>(src, E, gwp0, gbp0, uwp0, ubp0, gwp1, gbp1, uwp1, ubp1,
                   cw, cb, out, Mh, Ml, pg0, pu0, pg1, pu1, wsp, off0, false, stream);
  }
}

// Round 8
// 53853.094 us; speedup vs baseline: 1.6954x; 1.0004x over previous
//
#include <hip/hip_runtime.h>
#include <hip/hip_bf16.h>
#include <math.h>

#define NN 2000
#define DD 16
#define BB 64
#define TT 12
#define HH 64
#define MR 4000   // rows of stacked M = [A ; 2A^2 - I]
#define SCL 2048.0f
#define ISCL (1.0f / 2048.0f)

typedef _Float16 f16;
typedef __attribute__((ext_vector_type(8))) _Float16 frag8h;  // 8 f16 = 4 VGPRs
typedef __attribute__((ext_vector_type(4))) float floatx4;

__device__ inline float fin(float v) {
  return (v == v && v > -1e30f && v < 1e30f) ? v : 0.f;
}
__device__ inline float sigmoid_safe(float x) {
  float e = expf(-fabsf(x));
  float s = 1.f / (1.f + e);
  return x >= 0.f ? s : 1.f - s;
}
__device__ inline float tanh_safe(float x) {
  float e = expf(-2.f * fabsf(x));
  float r = (1.f - e) / (1.f + e);
  return x >= 0.f ? r : -r;
}
// split v = hi + lo/2048, hi/lo f16
__device__ inline void split16(float v, f16& hi, f16& lo) {
  hi = (f16)v;
  lo = (f16)((v - (float)hi) * SCL);
}
// async global->LDS 16B: lands at (wave-uniform) l + lane*16
__device__ inline void gll16(const void* g, void* l) {
  __builtin_amdgcn_global_load_lds((const __attribute__((address_space(1))) void*)g,
                                   (__attribute__((address_space(3))) void*)l, 16, 0, 0);
}

__global__ void kzero(float* p, int n) {
  int i = blockIdx.x * 256 + threadIdx.x;
  if (i < n) p[i] = 0.f;
}

// ---- A = softmax(relu(E E^T), axis=1); all f32 ----
__global__ __launch_bounds__(256) void ka(const float* __restrict__ E,
                                          float* __restrict__ A) {
  __shared__ float s[NN];
  __shared__ float red[256];
  int n = blockIdx.x;
  float en[DD];
#pragma unroll
  for (int d = 0; d < DD; ++d) en[d] = fin(E[n * DD + d]);
  float lmax = 0.f;
  for (int m = threadIdx.x; m < NN; m += 256) {
    float acc = 0.f;
#pragma unroll
    for (int d = 0; d < DD; ++d) acc += en[d] * fin(E[m * DD + d]);
    acc = fmaxf(acc, 0.f);
    s[m] = acc;
    lmax = fmaxf(lmax, acc);
  }
  red[threadIdx.x] = lmax;
  __syncthreads();
  for (int w = 128; w > 0; w >>= 1) {
    if (threadIdx.x < w) red[threadIdx.x] = fmaxf(red[threadIdx.x], red[threadIdx.x + w]);
    __syncthreads();
  }
  float mx = red[0];
  __syncthreads();
  float lsum = 0.f;
  for (int m = threadIdx.x; m < NN; m += 256) {
    float e = expf(s[m] - mx);
    s[m] = e;
    lsum += e;
  }
  red[threadIdx.x] = lsum;
  __syncthreads();
  for (int w = 128; w > 0; w >>= 1) {
    if (threadIdx.x < w) red[threadIdx.x] += red[threadIdx.x + w];
    __syncthreads();
  }
  float inv = 1.f / red[0];
  for (int m = threadIdx.x; m < NN; m += 256) A[(size_t)n * NN + m] = s[m] * inv;
}

// ---- C(NN x cols) = A @ V ; f32, 64x64 tile (prologue only, for A^2) ----
#define TM 64
#define TK 32
__global__ __launch_bounds__(256) void kg(const float* __restrict__ A,
                                          const float* __restrict__ V,
                                          float* __restrict__ C, int cols) {
  __shared__ float As[TK][TM + 1];
  __shared__ float Bs[TK][TM + 1];
  int r0 = blockIdx.x * TM;
  int c0 = blockIdx.y * TM;
  int tid = threadIdx.x;
  int tx = tid % 16;
  int ty = tid / 16;
  float acc[4][4];
#pragma unroll
  for (int i = 0; i < 4; ++i)
#pragma unroll
    for (int j = 0; j < 4; ++j) acc[i][j] = 0.f;
  for (int k0 = 0; k0 < NN; k0 += TK) {
    for (int i = tid; i < TM * TK; i += 256) {
      int rr = i / TK, kk = i % TK;
      int gr = r0 + rr, gk = k0 + kk;
      As[kk][rr] = (gr < NN && gk < NN) ? A[(size_t)gr * NN + gk] : 0.f;
    }
    for (int i = tid; i < TK * TM; i += 256) {
      int kk = i / TM, cc = i % TM;
      int gk = k0 + kk, gc = c0 + cc;
      Bs[kk][cc] = (gk < NN && gc < cols) ? V[(size_t)gk * cols + gc] : 0.f;
    }
    __syncthreads();
#pragma unroll 4
    for (int kk = 0; kk < TK; ++kk) {
      float a[4], b[4];
#pragma unroll
      for (int i = 0; i < 4; ++i) a[i] = As[kk][ty * 4 + i];
#pragma unroll
      for (int j = 0; j < 4; ++j) b[j] = Bs[kk][tx * 4 + j];
#pragma unroll
      for (int i = 0; i < 4; ++i)
#pragma unroll
        for (int j = 0; j < 4; ++j) acc[i][j] += a[i] * b[j];
    }
    __syncthreads();
  }
#pragma unroll
  for (int i = 0; i < 4; ++i) {
    int gr = r0 + ty * 4 + i;
    if (gr >= NN) continue;
#pragma unroll
    for (int j = 0; j < 4; ++j) {
      int gc = c0 + tx * 4 + j;
      if (gc < cols) C[(size_t)gr * cols + gc] = acc[i][j];
    }
  }
}

// ---- build split M = [A ; 2A^2 - I] as f16 hi + lo/2048 ----
__global__ void ksplitM(const float* __restrict__ A, const float* __restrict__ A2,
                        f16* __restrict__ Mh, f16* __restrict__ Ml) {
  int i = blockIdx.x * 256 + threadIdx.x;
  if (i >= MR * NN) return;
  int m = i / NN;
  int k = i % NN;
  float v;
  if (m < NN) v = A[(size_t)m * NN + k];
  else {
    int mm = m - NN;
    v = 2.f * A2[(size_t)mm * NN + k] - (mm == k ? 1.f : 0.f);
  }
  f16 hi, lo;
  split16(v, hi, lo);
  Mh[i] = hi;
  Ml[i] = lo;
}

// ---- split+transpose: V f32 [2000][cols] -> Th/Tl f16 [cols][2000] ----
__global__ __launch_bounds__(256) void kconvT(const float* __restrict__ V,
                                              f16* __restrict__ Th,
                                              f16* __restrict__ Tl, int cols) {
  __shared__ float sh[32][33];
  int k0 = blockIdx.x * 32;
  int c0 = blockIdx.y * 32;
  int tx = threadIdx.x % 32;
  int ty = threadIdx.x / 32;  // 0..7
#pragma unroll
  for (int i = 0; i < 4; ++i) {
    int r = k0 + ty + i * 8;
    int c = c0 + tx;
    sh[ty + i * 8][tx] = (r < NN && c < cols) ? V[(size_t)r * cols + c] : 0.f;
  }
  __syncthreads();
#pragma unroll
  for (int i = 0; i < 4; ++i) {
    int cc = c0 + ty + i * 8;
    int kk = k0 + tx;
    if (cc < cols && kk < NN) {
      f16 hi, lo;
      split16(sh[tx][ty + i * 8], hi, lo);
      Th[(size_t)cc * NN + kk] = hi;
      Tl[(size_t)cc * NN + kk] = lo;
    }
  }
}

// ---- MFMA GEMM: FROZEN at the best-measured config (54.50 ms, R0-output).
// 128x128 tile, 4 waves (2x2), per-wave 64x64, dual f32 accumulators,
// single-buffer LDS, __syncthreads per K-step, XCD bijective swizzle.
// Probe record: R1 counted-vmcnt dbuf = null; R3 128x256 1-block/CU = -35%;
// R4 single-acc 12w/CU = null; R5/R6 256x128 = -65% (VGPR spill). Do not
// touch this kernel again without per-dispatch counters.
#define KT 32
__global__ __launch_bounds__(256, 2) void kmm(const f16* __restrict__ Mh,
                                              const f16* __restrict__ Ml,
                                              const f16* __restrict__ Bh,
                                              const f16* __restrict__ Bl,
                                              float* __restrict__ C1,
                                              float* __restrict__ C2, int cols) {
  __shared__ __align__(16) f16 Ash[128 * KT];
  __shared__ __align__(16) f16 Asl[128 * KT];
  __shared__ __align__(16) f16 Bsh[128 * KT];
  __shared__ __align__(16) f16 Bsl[128 * KT];
  int tid = threadIdx.x;
  int lane = tid & 63;
  int wave = tid >> 6;
  int wr = wave >> 1;   // 0..1
  int wc = wave & 1;    // 0..1
  // XCD swizzle: bijective contiguous-chunk remap (m204) for B-panel L2 reuse.
  int gx = gridDim.x;
  int nwg = gx * gridDim.y;
  int wg = blockIdx.y * gx + blockIdx.x;
  int q = nwg >> 3, r = nwg & 7;
  int xcd = wg & 7, lid = wg >> 3;
  int swz = (xcd < r ? xcd * (q + 1) : r * (q + 1) + (xcd - r) * q) + lid;
  int bx = swz % gx;
  int by = swz / gx;
  floatx4 acc0[4][4], acc1[4][4];
#pragma unroll
  for (int i = 0; i < 4; ++i)
#pragma unroll
    for (int j = 0; j < 4; ++j) {
      acc0[i][j] = (floatx4){0.f, 0.f, 0.f, 0.f};
      acc1[i][j] = (floatx4){0.f, 0.f, 0.f, 0.f};
    }
  const frag8h zf = {0, 0, 0, 0, 0, 0, 0, 0};

  auto comp = [&]() {
    frag8h ah[4], al[4], bh[4], bl[4];
#pragma unroll
    for (int mi = 0; mi < 4; ++mi) {
      int jr = wr * 4 + mi;                       // region index (16 rows each)
      ah[mi] = *(const frag8h*)(&Ash[jr * 512 + lane * 8]);
      al[mi] = *(const frag8h*)(&Asl[jr * 512 + lane * 8]);
    }
#pragma unroll
    for (int ni = 0; ni < 4; ++ni) {
      int jc = wc * 4 + ni;
      bh[ni] = *(const frag8h*)(&Bsh[jc * 512 + lane * 8]);
      bl[ni] = *(const frag8h*)(&Bsl[jc * 512 + lane * 8]);
    }
#pragma unroll
    for (int mi = 0; mi < 4; ++mi)
#pragma unroll
      for (int ni = 0; ni < 4; ++ni) {
        acc0[mi][ni] = __builtin_amdgcn_mfma_f32_16x16x32_f16(ah[mi], bh[ni], acc0[mi][ni], 0, 0, 0);
        acc1[mi][ni] = __builtin_amdgcn_mfma_f32_16x16x32_f16(ah[mi], bl[ni], acc1[mi][ni], 0, 0, 0);
        acc1[mi][ni] = __builtin_amdgcn_mfma_f32_16x16x32_f16(al[mi], bh[ni], acc1[mi][ni], 0, 0, 0);
      }
  };

  const int lr = lane & 15;   // row within region this lane stages
  const int lq = lane >> 4;   // k-chunk this lane stages
  // fast path: full 32-k tiles via global_load_lds
  for (int k0 = 0; k0 + KT <= NN; k0 += KT) {
#pragma unroll
    for (int jj = 0; jj < 2; ++jj) {
      int j = wave * 2 + jj;            // region 0..7
      int r2 = j * 16 + lr;
      size_t ko = (size_t)k0 + lq * 8;
      int gra = bx * 128 + r2;
      if (gra < MR) {
        gll16(Mh + (size_t)gra * NN + ko, Ash + j * 512);
        gll16(Ml + (size_t)gra * NN + ko, Asl + j * 512);
      }
      int grb = by * 128 + r2;
      if (grb < cols) {
        gll16(Bh + (size_t)grb * NN + ko, Bsh + j * 512);
        gll16(Bl + (size_t)grb * NN + ko, Bsl + j * 512);
      }
    }
    __syncthreads();
    comp();
    __syncthreads();
  }
  // tail (k0 = 1984, 16 valid k): guarded VGPR staging, same slot layout
  {
    int k0 = (NN / KT) * KT;
    if (k0 < NN) {
      for (int c = tid; c < 512; c += 256) {
        int j = c >> 6;          // region
        int ll = c & 63;         // slot within region
        int qq = ll >> 4;
        int rr = ll & 15;
        int r2 = j * 16 + rr;
        int gk = k0 + qq * 8;
        bool kok = (gk + 8 <= NN);
        int gra = bx * 128 + r2;
        bool aok = kok && (gra < MR);
        size_t ga = (size_t)gra * NN + gk;
        *(frag8h*)(&Ash[c * 8]) = aok ? *(const frag8h*)(Mh + ga) : zf;
        *(frag8h*)(&Asl[c * 8]) = aok ? *(const frag8h*)(Ml + ga) : zf;
        int grb = by * 128 + r2;
        bool bok = kok && (grb < cols);
        size_t gb = (size_t)grb * NN + gk;
        *(frag8h*)(&Bsh[c * 8]) = bok ? *(const frag8h*)(Bh + gb) : zf;
        *(frag8h*)(&Bsl[c * 8]) = bok ? *(const frag8h*)(Bl + gb) : zf;
      }
      __syncthreads();
      comp();
      __syncthreads();
    }
  }
  // store: C/D layout col = lane&15, row = (lane>>4)*4 + reg
#pragma unroll
  for (int mi = 0; mi < 4; ++mi) {
#pragma unroll
    for (int ni = 0; ni < 4; ++ni) {
#pragma unroll
      for (int reg = 0; reg < 4; ++reg) {
        int row = bx * 128 + wr * 64 + mi * 16 + (lane >> 4) * 4 + reg;
        int col = by * 128 + wc * 64 + ni * 16 + (lane & 15);
        if (col >= cols || row >= MR) continue;
        float v = acc0[mi][ni][reg] + acc1[mi][ni][reg] * ISCL;
        if (row < NN) C1[(size_t)row * cols + col] = v;
        else C2[(size_t)(row - NN) * cols + col] = v;
      }
    }
  }
}

// ---- xb[n*CB + bb] = src[((b0+bb)*TT + t)*NN + n] (tight path) ----
__global__ void kx(const float* __restrict__ src, float* __restrict__ xb,
                   int t, int b0, int CB) {
  int i = blockIdx.x * 256 + threadIdx.x;
  if (i >= NN * CB) return;
  int bb = i % CB;
  int n = i / CB;
  xb[i] = fin(src[((size_t)(b0 + bb) * TT + t) * NN + n]);
}

// ---- batched: xa[n*(TT*CB) + t*CB + bb] = src[((b0+bb)*TT + t)*NN + n] ----
__global__ void kxa(const float* __restrict__ src, float* __restrict__ xa,
                    int b0, int CB) {
  int i = blockIdx.x * 256 + threadIdx.x;
  if (i >= NN * TT * CB) return;
  int bb = i % CB;
  int t = (i / CB) % TT;
  int n = i / (CB * TT);
  xa[i] = fin(src[((size_t)(b0 + bb) * TT + t) * NN + n]);
}

// ---- zb[i] *= h[i] (legacy path only) ----
__global__ void kmulz(float* __restrict__ zb, const float* __restrict__ h, int n) {
  int i = blockIdx.x * 256 + threadIdx.x;
  if (i < n) zb[i] = zb[i] * h[i];
}

// ---- precompute per-node combined weights W[n,k,c,o] = sum_d E[n,d]*wp[d,k,c,o].
__global__ __launch_bounds__(256) void kwc(const float* __restrict__ E,
                                           const float* __restrict__ wp,
                                           int Ctot, int O, float* __restrict__ W) {
  __shared__ float esm[DD];
  int n = blockIdx.x;
  int tid = threadIdx.x;
  if (tid < DD) esm[tid] = fin(E[n * DD + tid]);
  __syncthreads();
  int total = 3 * Ctot * O;
  for (int i = tid; i < total; i += 256) {
    int o = i % O;
    int rc = i / O;              // k*Ctot + crow
    int k = rc / Ctot;
    int crow = rc - k * Ctot;
    float wa = 0.f;
#pragma unroll
    for (int d = 0; d < DD; ++d)
      wa += esm[d] * fin(wp[((size_t)(d * 3 + k) * Ctot + crow) * O + o]);
    W[((size_t)(n * 3 + k) * Ctot + crow) * O + o] = wa;
  }
}

// ---- gconv (chunk=16). ldn = per-node row stride of x. ----
template <int O, int CB>
__global__ __launch_bounds__(256) void kgc(
    const float* __restrict__ x0, const float* __restrict__ x1, const float* __restrict__ x2,
    const float* __restrict__ wp, const float* __restrict__ pW,
    int Ctot, int base_c, int nC, int ldn,
    const float* __restrict__ E, const float* __restrict__ bp,
    int act, int accum, float* outA, float* outB,
    int update, const float* __restrict__ rb, float* hio) {
  __shared__ float xs[16][CB + 1];
  __shared__ float ws[16][O];
  __shared__ float esm[DD];
  int n = blockIdx.x;
  int tid = threadIdx.x;
  int to = tid % 16;
  int tb = tid / 16;
  if (tid < DD) esm[tid] = fin(E[n * DD + tid]);
  __syncthreads();
  constexpr int NO = O / 16;
  constexpr int NB = CB / 16;
  float acc[NB][NO];
#pragma unroll
  for (int i = 0; i < NB; ++i)
#pragma unroll
    for (int j = 0; j < NO; ++j) acc[i][j] = 0.f;
  const size_t nb = (size_t)n * CB;
  const size_t nx = (size_t)n * ldn;
  for (int k = 0; k < 3; ++k) {
    const float* xk = (k == 0) ? x0 : (k == 1) ? x1 : x2;
    for (int c0 = 0; c0 < nC; c0 += 16) {
      int chunk = (nC - c0 < 16) ? (nC - c0) : 16;
      for (int i = tid; i < chunk * CB; i += 256) {
        int cc = i % chunk;
        int b = i / chunk;
        xs[cc][b] = xk[nx + (size_t)b * nC + c0 + cc];
      }
      if (pW) {
        const float* wrow = pW + ((size_t)(n * 3 + k) * Ctot + base_c + c0) * O;
        for (int i = tid; i < chunk * O; i += 256) {
          int o = i % O;
          int cc = i / O;
          ws[cc][o] = wrow[(size_t)cc * O + o];
        }
      } else {
        for (int i = tid; i < chunk * O; i += 256) {
          int o = i % O;
          int cc = i / O;
          int crow = base_c + c0 + cc;
          float wa = 0.f;
#pragma unroll
          for (int d = 0; d < DD; ++d)
            wa += esm[d] * fin(wp[((size_t)(d * 3 + k) * Ctot + crow) * O + o]);
          ws[cc][o] = wa;
        }
      }
      __syncthreads();
      for (int cc = 0; cc < chunk; ++cc) {
        float xv[NB];
#pragma unroll
        for (int i = 0; i < NB; ++i) xv[i] = xs[cc][tb + 16 * i];
#pragma unroll
        for (int j = 0; j < NO; ++j) {
          float wv = ws[cc][to + 16 * j];
#pragma unroll
          for (int i = 0; i < NB; ++i) acc[i][j] += xv[i] * wv;
        }
      }
      __syncthreads();
    }
  }
#pragma unroll
  for (int i2 = 0; i2 < NB; ++i2) {
    int b = tb + 16 * i2;
#pragma unroll
    for (int j = 0; j < NO; ++j) {
      int o = to + 16 * j;
      float r = acc[i2][j];
      float* dst = (o < HH || !outB) ? (outA + (nb + b) * HH + (o % HH))
                                     : (outB + (nb + b) * HH + (o - HH));
      if (accum) r += *dst;
      if (bp) {
        float ba = 0.f;
#pragma unroll
        for (int d = 0; d < DD; ++d) ba += esm[d] * fin(bp[d * O + o]);
        r += ba;
      }
      r = fin(r);
      if (act == 1) r = sigmoid_safe(r);
      else if (act == 2) r = tanh_safe(r);
      if (update) {
        float rg = rb[(nb + b) * HH + o];
        float hold = hio[(nb + b) * HH + o];
        hio[(nb + b) * HH + o] = rg * hold + (1.f - rg) * r;
      } else {
        *dst = r;
      }
    }
  }
}

// ---- fused kernel: gate(h-part) + gate(x-part) + update(x-part), with the
// z*h elementwise product fused into the epilogue (hmul = the layer's h).
// zb receives sigmoid(gate_z) * hmul; rbf receives sigmoid(gate_r);
// hc receives the raw update x-part. Replaces 3 kgc + 1 kmulz launches.
template <int CB>
__global__ __launch_bounds__(256) void kgf(
    const float* __restrict__ A0, const float* __restrict__ A1, const float* __restrict__ A2,
    int nCA, int baseA, int ldA,
    const float* __restrict__ B0, const float* __restrict__ B1, const float* __restrict__ B2,
    int nCB, int baseB, int ldB,
    const float* __restrict__ wpg, const float* __restrict__ pWg,
    const float* __restrict__ bpg,
    const float* __restrict__ wpu, const float* __restrict__ pWu,
    int Ctot, const float* __restrict__ E, const float* __restrict__ hmul,
    float* __restrict__ zb, float* __restrict__ rbf, float* __restrict__ hc) {
  __shared__ float xs[16][CB + 1];
  __shared__ float wsg[16][128];
  __shared__ float wsu[16][64];
  __shared__ float esm[DD];
  int n = blockIdx.x;
  int tid = threadIdx.x;
  int to = tid % 16;
  int tb = tid / 16;
  if (tid < DD) esm[tid] = fin(E[n * DD + tid]);
  __syncthreads();
  constexpr int NB = CB / 16;
  float accg[NB][8];
  float accu[NB][4];
#pragma unroll
  for (int i = 0; i < NB; ++i) {
#pragma unroll
    for (int j = 0; j < 8; ++j) accg[i][j] = 0.f;
#pragma unroll
    for (int j = 0; j < 4; ++j) accu[i][j] = 0.f;
  }
  const size_t nb = (size_t)n * CB;

  // ---- pass A: gate only ----
  {
    const size_t nx = (size_t)n * ldA;
    for (int k = 0; k < 3; ++k) {
      const float* xk = (k == 0) ? A0 : (k == 1) ? A1 : A2;
      for (int c0 = 0; c0 < nCA; c0 += 16) {
        int chunk = (nCA - c0 < 16) ? (nCA - c0) : 16;
        for (int i = tid; i < chunk * CB; i += 256) {
          int cc = i % chunk;
          int b = i / chunk;
          xs[cc][b] = xk[nx + (size_t)b * nCA + c0 + cc];
        }
        if (pWg) {
          const float* wrow = pWg + ((size_t)(n * 3 + k) * Ctot + baseA + c0) * 128;
          for (int i = tid; i < chunk * 128; i += 256) {
            int o = i % 128;
            int cc = i / 128;
            wsg[cc][o] = wrow[(size_t)cc * 128 + o];
          }
        } else {
          for (int i = tid; i < chunk * 128; i += 256) {
            int o = i % 128;
            int cc = i / 128;
            int crow = baseA + c0 + cc;
            float wa = 0.f;
#pragma unroll
            for (int d = 0; d < DD; ++d)
              wa += esm[d] * fin(wpg[((size_t)(d * 3 + k) * Ctot + crow) * 128 + o]);
            wsg[cc][o] = wa;
          }
        }
        __syncthreads();
        for (int cc = 0; cc < chunk; ++cc) {
          float xv[NB];
#pragma unroll
          for (int i = 0; i < NB; ++i) xv[i] = xs[cc][tb + 16 * i];
#pragma unroll
          for (int j = 0; j < 8; ++j) {
            float wv = wsg[cc][to + 16 * j];
#pragma unroll
            for (int i = 0; i < NB; ++i) accg[i][j] += xv[i] * wv;
          }
        }
        __syncthreads();
      }
    }
  }
  // ---- pass B: gate + update ----
  {
    const size_t nx = (size_t)n * ldB;
    for (int k = 0; k < 3; ++k) {
      const float* xk = (k == 0) ? B0 : (k == 1) ? B1 : B2;
      for (int c0 = 0; c0 < nCB; c0 += 16) {
        int chunk = (nCB - c0 < 16) ? (nCB - c0) : 16;
        for (int i = tid; i < chunk * CB; i += 256) {
          int cc = i % chunk;
          int b = i / chunk;
          xs[cc][b] = xk[nx + (size_t)b * nCB + c0 + cc];
        }
        if (pWg) {
          const float* wrow = pWg + ((size_t)(n * 3 + k) * Ctot + baseB + c0) * 128;
          for (int i = tid; i < chunk * 128; i += 256) {
            int o = i % 128;
            int cc = i / 128;
            wsg[cc][o] = wrow[(size_t)cc * 128 + o];
          }
        } else {
          for (int i = tid; i < chunk * 128; i += 256) {
            int o = i % 128;
            int cc = i / 128;
            int crow = baseB + c0 + cc;
            float wa = 0.f;
#pragma unroll
            for (int d = 0; d < DD; ++d)
              wa += esm[d] * fin(wpg[((size_t)(d * 3 + k) * Ctot + crow) * 128 + o]);
            wsg[cc][o] = wa;
          }
        }
        if (pWu) {
          const float* wrow = pWu + ((size_t)(n * 3 + k) * Ctot + baseB + c0) * 64;
          for (int i = tid; i < chunk * 64; i += 256) {
            int o = i % 64;
            int cc = i / 64;
            wsu[cc][o] = wrow[(size_t)cc * 64 + o];
          }
        } else {
          for (int i = tid; i < chunk * 64; i += 256) {
            int o = i % 64;
            int cc = i / 64;
            int crow = baseB + c0 + cc;
            float wa = 0.f;
#pragma unroll
            for (int d = 0; d < DD; ++d)
              wa += esm[d] * fin(wpu[((size_t)(d * 3 + k) * Ctot + crow) * 64 + o]);
            wsu[cc][o] = wa;
          }
        }
        __syncthreads();
        for (int cc = 0; cc < chunk; ++cc) {
          float xv[NB];
#pragma unroll
          for (int i = 0; i < NB; ++i) xv[i] = xs[cc][tb + 16 * i];
#pragma unroll
          for (int j = 0; j < 8; ++j) {
            float wv = wsg[cc][to + 16 * j];
#pragma unroll
            for (int i = 0; i < NB; ++i) accg[i][j] += xv[i] * wv;
          }
#pragma unroll
          for (int j = 0; j < 4; ++j) {
            float wv = wsu[cc][to + 16 * j];
#pragma unroll
            for (int i = 0; i < NB; ++i) accu[i][j] += xv[i] * wv;
          }
        }
        __syncthreads();
      }
    }
  }
  // ---- epilogue ----
#pragma unroll
  for (int i2 = 0; i2 < NB; ++i2) {
    int b = tb + 16 * i2;
#pragma unroll
    for (int j = 0; j < 8; ++j) {
      int o = to + 16 * j;
      float r = accg[i2][j];
      float ba = 0.f;
#pragma unroll
      for (int d = 0; d < DD; ++d) ba += esm[d] * fin(bpg[d * 128 + o]);
      r = fin(r + ba);
      r = sigmoid_safe(r);
      if (o < HH) zb[(nb + b) * HH + o] = r * hmul[(nb + b) * HH + o];
      else rbf[(nb + b) * HH + (o - HH)] = r;
    }
#pragma unroll
    for (int j = 0; j < 4; ++j) {
      int o = to + 16 * j;
      hc[(nb + b) * HH + o] = fin(accu[i2][j]);
    }
  }
}

// ---- out[(b0+bb), o, n] = sum_h h1[n,bb,h]*cw[o*H+h] + cb[o] ----
__global__ void kfin(const float* __restrict__ h1, const float* __restrict__ cw,
                     const float* __restrict__ cb, float* __restrict__ out,
                     int b0, int CB) {
  int idx = blockIdx.x * 256 + threadIdx.x;
  if (idx >= CB * TT * NN) return;
  int n = idx % NN;
  int o = (idx / NN) % TT;
  int bb = idx / (NN * TT);
  const float* hp = h1 + ((size_t)n * CB + bb) * HH;
  float acc = fin(cb[o]);
#pragma unroll
  for (int hh = 0; hh < HH; ++hh) acc += hp[hh] * fin(cw[o * HH + hh]);
  out[((size_t)(b0 + bb) * TT + o) * NN + n] = fin(acc);
}

// Scheduling notes:
//  * h0 mutated only at end of layer 0 -> cache its chain (P1c/P2c, roomy).
//  * t=0: h0=h1=0, zb=z*h=0 -> zero-input chains replaced by zero buffers.
//  * kgf fuses {gate-h, gate-x, update-x, z*=h} per layer-timestep.
//  * h0/h1 are contiguous (NC*4 multiple of 256) -> single kzero over both.
template <int CB>
static void run_chunks(const float* src, const float* E,
                       const float* gwp0, const float* gbp0,
                       const float* uwp0, const float* ubp0,
                       const float* gwp1, const float* gbp1,
                       const float* uwp1, const float* ubp1,
                       const float* cw, const float* cb,
                       float* out, f16* Mh, f16* Ml,
                       const float* pg0, const float* pu0,
                       const float* pg1, const float* pu1,
                       char* wsp, size_t off0, bool roomy, hipStream_t stream) {
  size_t off = off0;
  auto allocf = [&](size_t nelem) {
    float* p = (float*)(wsp + off);
    off += (nelem * 4 + 255) & ~(size_t)255;
    return p;
  };
  auto alloch = [&](size_t nelem) {
    f16* p = (f16*)(wsp + off);
    off += (nelem * 2 + 255) & ~(size_t)255;
    return p;
  };
  const int C = CB * HH;
  const int XC = TT * CB;
  const size_t NC = (size_t)NN * C;
  float* P1  = allocf(NC);
  float* P2  = allocf(NC);
  float* h0  = allocf(NC);   // h0,h1 contiguous (NC*4 is 256-divisible)
  float* h1  = allocf(NC);
  float* zb  = allocf(NC);
  float* rbf = allocf(NC);
  float* hc  = allocf(NC);
  f16* vh = alloch(NC);
  f16* vl = alloch(NC);
  float *P1c = nullptr, *P2c = nullptr;
  float *xa = nullptr, *xb1a = nullptr, *xb2a = nullptr;
  float *xb0 = nullptr, *xb1 = nullptr, *xb2 = nullptr;
  f16 *xth, *xtl;
  if (roomy) {
    P1c = allocf(NC);
    P2c = allocf(NC);
    xa   = allocf((size_t)NN * XC);
    xb1a = allocf((size_t)NN * XC);
    xb2a = allocf((size_t)NN * XC);
    xth = alloch((size_t)NN * XC);
    xtl = alloch((size_t)NN * XC);
  } else {
    xb0 = allocf((size_t)NN * CB);
    xb1 = allocf((size_t)NN * CB);
    xb2 = allocf((size_t)NN * CB);
    xth = alloch((size_t)NN * CB);
    xtl = alloch((size_t)NN * CB);
  }

  const int EW = (int)((NC + 255) / 256);
  const dim3 gConv((NN + 31) / 32, (C + 31) / 32);
  const dim3 gMM((MR + 127) / 128, (C + 127) / 128);
  float* nul = nullptr;

  auto chain_to = [&](const float* V, float* D1, float* D2) {
    kconvT<<<gConv, 256, 0, stream>>>(V, vh, vl, C);
    kmm<<<gMM, 256, 0, stream>>>(Mh, Ml, vh, vl, D1, D2, C);
  };

  for (int b0 = 0; b0 < BB; b0 += CB) {
    kzero<<<2 * EW, 256, 0, stream>>>(h0, (int)(2 * NC));   // h0+h1 contiguous
    if (roomy) {
      kxa<<<((NN * XC) + 255) / 256, 256, 0, stream>>>(src, xa, b0, CB);
      dim3 gcx((NN + 31) / 32, (XC + 31) / 32);
      kconvT<<<gcx, 256, 0, stream>>>(xa, xth, xtl, XC);
      dim3 gmx((MR + 127) / 128, (XC + 127) / 128);
      kmm<<<gmx, 256, 0, stream>>>(Mh, Ml, xth, xtl, xb1a, xb2a, XC);
    }
    for (int t = 0; t < TT; ++t) {
      const bool tz = (t == 0);
      const float *xt0, *xt1, *xt2;
      int xln;
      if (roomy) {
        xt0 = xa + t * CB;
        xt1 = xb1a + t * CB;
        xt2 = xb2a + t * CB;
        xln = XC;
      } else {
        kx<<<(NN * CB + 255) / 256, 256, 0, stream>>>(src, xb0, t, b0, CB);
        dim3 gcx((NN + 31) / 32, (CB + 31) / 32);
        kconvT<<<gcx, 256, 0, stream>>>(xb0, xth, xtl, CB);
        dim3 gmx((MR + 127) / 128, (CB + 127) / 128);
        kmm<<<gmx, 256, 0, stream>>>(Mh, Ml, xth, xtl, xb1, xb2, CB);
        xt0 = xb0; xt1 = xb1; xt2 = xb2;
        xln = CB;
      }
      // ===== layer 0 (Ctot=65): fused gate+updateX+(z*=h0) =====
      const float *g1, *g2;
      if (tz) { g1 = h0; g2 = h0; }                 // h0 == 0: chains are zero
      else if (roomy) { g1 = P1c; g2 = P2c; }        // cached from prev t layer1
      else { chain_to(h0, P1, P2); g1 = P1; g2 = P2; }
      kgf<CB><<<NN, 256, 0, stream>>>(h0, g1, g2, 64, 1, C,
                                      xt0, xt1, xt2, 1, 0, xln,
                                      gwp0, pg0, gbp0, uwp0, pu0, 65, E, h0,
                                      zb, rbf, hc);
      if (tz) {  // zb = z*0 = 0
        kgc<64, CB><<<NN, 256, 0, stream>>>(zb, zb, zb, uwp0, pu0, 65, 1, 64, C, E, ubp0,
                                            2, 1, hc, nul, 1, rbf, h0);
      } else {
        chain_to(zb, P1, P2);
        kgc<64, CB><<<NN, 256, 0, stream>>>(zb, P1, P2, uwp0, pu0, 65, 1, 64, C, E, ubp0,
                                            2, 1, hc, nul, 1, rbf, h0);
      }
      // ===== layer 1 (x = h0 new, Ctot=128) =====
      if (roomy) {
        const float *a1, *a2;
        if (tz) { a1 = h1; a2 = h1; }
        else { chain_to(h1, P1, P2); a1 = P1; a2 = P2; }
        chain_to(h0, P1c, P2c);   // also cached for next t layer 0
        kgf<CB><<<NN, 256, 0, stream>>>(h1, a1, a2, 64, 64, C,
                                        h0, P1c, P2c, 64, 0, C,
                                        gwp1, pg1, gbp1, uwp1, pu1, 128, E, h1,
                                        zb, rbf, hc);
      } else {
        if (tz) {
          kgc<128, CB><<<NN, 256, 0, stream>>>(h1, h1, h1, gwp1, pg1, 128, 64, 64, C, E, nullptr,
                                               0, 0, zb, rbf, 0, nul, nul);
        } else {
          chain_to(h1, P1, P2);
          kgc<128, CB><<<NN, 256, 0, stream>>>(h1, P1, P2, gwp1, pg1, 128, 64, 64, C, E, nullptr,
                                               0, 0, zb, rbf, 0, nul, nul);
        }
        chain_to(h0, P1, P2);
        kgc<128, CB><<<NN, 256, 0, stream>>>(h0, P1, P2, gwp1, pg1, 128, 0, 64, C, E, gbp1,
                                             1, 1, zb, rbf, 0, nul, nul);
        kgc<64, CB><<<NN, 256, 0, stream>>>(h0, P1, P2, uwp1, pu1, 128, 0, 64, C, E, nullptr,
                                            0, 0, hc, nul, 0, nul, nul);
        kmulz<<<EW, 256, 0, stream>>>(zb, h1, (int)NC);
      }
      if (tz) {  // zb = z*0 = 0
        kgc<64, CB><<<NN, 256, 0, stream>>>(zb, zb, zb, uwp1, pu1, 128, 64, 64, C, E, ubp1,
                                            2, 1, hc, nul, 1, rbf, h1);
      } else {
        chain_to(zb, P1, P2);
        kgc<64, CB><<<NN, 256, 0, stream>>>(zb, P1, P2, uwp1, pu1, 128, 64, 64, C, E, ubp1,
                                            2, 1, hc, nul, 1, rbf, h1);
      }
    }
    kfin<<<(CB * TT * NN + 255) / 256, 256, 0, stream>>>(h1, cw, cb, out, b0, CB);
  }
}

extern "C" void kernel_launch(void* const* d_in, const int* in_sizes, int n_in,
                              void* d_out, int out_size, void* d_ws, size_t ws_size,
                              hipStream_t stream) {
  const float* src  = (const float*)d_in[0];
  const float* E    = (const float*)d_in[1];
  const float* gwp0 = (const float*)d_in[2];
  const float* gbp0 = (const float*)d_in[3];
  const float* uwp0 = (const float*)d_in[4];
  const float* ubp0 = (const float*)d_in[5];
  const float* gwp1 = (const float*)d_in[6];
  const float* gbp1 = (const float*)d_in[7];
  const float* uwp1 = (const float*)d_in[8];
  const float* ubp1 = (const float*)d_in[9];
  const float* cw   = (const float*)d_in[10];
  const float* cb   = (const float*)d_in[11];
  float* out = (float*)d_out;
  (void)in_sizes; (void)n_in; (void)out_size;

  char* wsp = (char*)d_ws;
  size_t off = 0;
  f16* Mh = (f16*)(wsp + off); off += ((size_t)MR * NN * 2 + 255) & ~(size_t)255;
  f16* Ml = (f16*)(wsp + off); off += ((size_t)MR * NN * 2 + 255) & ~(size_t)255;

  // Optional precomputed combined-weight tensors (time-invariant, launch-lifetime).
  const size_t szg1 = (size_t)NN * 3 * 128 * 128;  // floats
  const size_t szu1 = (size_t)NN * 3 * 128 * 64;
  const size_t szg0 = (size_t)NN * 3 * 65 * 128;
  const size_t szu0 = (size_t)NN * 3 * 65 * 64;
  float *pg0 = nullptr, *pu0 = nullptr, *pg1 = nullptr, *pu1 = nullptr;
  bool wantAll = ws_size >= (size_t)1350 * 1000 * 1000;
  bool wantL1  = ws_size >= (size_t)1030 * 1000 * 1000;
  if (wantAll || wantL1) {
    pg1 = (float*)(wsp + off); off += (szg1 * 4 + 255) & ~(size_t)255;
    pu1 = (float*)(wsp + off); off += (szu1 * 4 + 255) & ~(size_t)255;
    if (wantAll) {
      pg0 = (float*)(wsp + off); off += (szg0 * 4 + 255) & ~(size_t)255;
      pu0 = (float*)(wsp + off); off += (szu0 * 4 + 255) & ~(size_t)255;
    }
  }
  size_t off0 = off;  // chunk area starts here
  // transient prologue buffers overlap the chunk area (dead before chunks start)
  float* A  = (float*)(wsp + off0);
  float* A2 = (float*)(wsp + off0 + (((size_t)NN * NN * 4 + 255) & ~(size_t)255));

  ka<<<NN, 256, 0, stream>>>(E, A);
  {
    dim3 g((NN + TM - 1) / TM, (NN + TM - 1) / TM);
    kg<<<g, 256, 0, stream>>>(A, A, A2, NN);
  }
  ksplitM<<<(MR * NN + 255) / 256, 256, 0, stream>>>(A, A2, Mh, Ml);
  if (pg1) {
    kwc<<<NN, 256, 0, stream>>>(E, gwp1, 128, 128, pg1);
    kwc<<<NN, 256, 0, stream>>>(E, uwp1, 128, 64, pu1);
  }
  if (pg0) {
    kwc<<<NN, 256, 0, stream>>>(E, gwp0, 65, 128, pg0);
    kwc<<<NN, 256, 0, stream>>>(E, uwp0, 65, 64, pu0);
  }

  // footprints past off0 (chunk area): CB=64 roomy ~353MB, tight ~265MB;
  // CB=32 roomy ~177MB, tight ~133MB; CB=16 roomy ~90MB, tight ~67MB.
  size_t rem = ws_size > off0 ? ws_size - off0 : 0;
  if (rem >= (size_t)368 * 1000 * 1000) {
    run_chunks<64>(src, E, gwp0, gbp0, uwp0, ubp0, gwp1, gbp1, uwp1, ubp1,
                   cw, cb, out, Mh, Ml, pg0, pu0, pg1, pu1, wsp, off0, true, stream);
  } else if (rem >= (size_t)288 * 1000 * 1000) {
    run_chunks<64>(src, E, gwp0, gbp0, uwp0, ubp0, gwp1, gbp1, uwp1, ubp1,
                   cw, cb, out, Mh, Ml, pg0, pu0, pg1, pu1, wsp, off0, false, stream);
  } else if (rem >= (size_t)193 * 1000 * 1000) {
    run_chunks<32>(src, E, gwp0, gbp0, uwp0, ubp0, gwp1, gbp1, uwp1, ubp1,
                   cw, cb, out, Mh, Ml, pg0, pu0, pg1, pu1, wsp, off0, true, stream);
  } else if (rem >= (size_t)153 * 1000 * 1000) {
    run_chunks<32>(src, E, gwp0, gbp0, uwp0, ubp0, gwp1, gbp1, uwp1, ubp1,
                   cw, cb, out, Mh, Ml, pg0, pu0, pg1, pu1, wsp, off0, false, stream);
  } else if (rem >= (size_t)98 * 1000 * 1000) {
    run_chunks<16>(src, E, gwp0, gbp0, uwp0, ubp0, gwp1, gbp1, uwp1, ubp1,
                   cw, cb, out, Mh, Ml, pg0, pu0, pg1, pu1, wsp, off0, true, stream);
  } else {
    run_chunks<16>(src, E, gwp0, gbp0, uwp0, ubp0, gwp1, gbp1, uwp1, ubp1,
                   cw, cb, out, Mh, Ml, pg0, pu0, pg1, pu1, wsp, off0, false, stream);
  }
}

// Round 10
// 53556.842 us; speedup vs baseline: 1.7048x; 1.0055x over previous
//
#include <hip/hip_runtime.h>
#include <hip/hip_bf16.h>
#include <math.h>

#define NN 2000
#define DD 16
#define BB 64
#define TT 12
#define HH 64
#define MR 4000   // rows of stacked M = [A ; 2A^2 - I]
#define SCL 2048.0f
#define ISCL (1.0f / 2048.0f)

typedef _Float16 f16;
typedef __attribute__((ext_vector_type(8))) _Float16 frag8h;  // 8 f16 = 4 VGPRs
typedef __attribute__((ext_vector_type(4))) float floatx4;

__device__ inline float fin(float v) {
  return (v == v && v > -1e30f && v < 1e30f) ? v : 0.f;
}
__device__ inline float sigmoid_safe(float x) {
  float e = expf(-fabsf(x));
  float s = 1.f / (1.f + e);
  return x >= 0.f ? s : 1.f - s;
}
__device__ inline float tanh_safe(float x) {
  float e = expf(-2.f * fabsf(x));
  float r = (1.f - e) / (1.f + e);
  return x >= 0.f ? r : -r;
}
// split v = hi + lo/2048, hi/lo f16
__device__ inline void split16(float v, f16& hi, f16& lo) {
  hi = (f16)v;
  lo = (f16)((v - (float)hi) * SCL);
}
// async global->LDS 16B: lands at (wave-uniform) l + lane*16
__device__ inline void gll16(const void* g, void* l) {
  __builtin_amdgcn_global_load_lds((const __attribute__((address_space(1))) void*)g,
                                   (__attribute__((address_space(3))) void*)l, 16, 0, 0);
}

__global__ void kzero(float* p, int n) {
  int i = blockIdx.x * 256 + threadIdx.x;
  if (i < n) p[i] = 0.f;
}

// ---- A = softmax(relu(E E^T), axis=1); all f32 ----
__global__ __launch_bounds__(256) void ka(const float* __restrict__ E,
                                          float* __restrict__ A) {
  __shared__ float s[NN];
  __shared__ float red[256];
  int n = blockIdx.x;
  float en[DD];
#pragma unroll
  for (int d = 0; d < DD; ++d) en[d] = fin(E[n * DD + d]);
  float lmax = 0.f;
  for (int m = threadIdx.x; m < NN; m += 256) {
    float acc = 0.f;
#pragma unroll
    for (int d = 0; d < DD; ++d) acc += en[d] * fin(E[m * DD + d]);
    acc = fmaxf(acc, 0.f);
    s[m] = acc;
    lmax = fmaxf(lmax, acc);
  }
  red[threadIdx.x] = lmax;
  __syncthreads();
  for (int w = 128; w > 0; w >>= 1) {
    if (threadIdx.x < w) red[threadIdx.x] = fmaxf(red[threadIdx.x], red[threadIdx.x + w]);
    __syncthreads();
  }
  float mx = red[0];
  __syncthreads();
  float lsum = 0.f;
  for (int m = threadIdx.x; m < NN; m += 256) {
    float e = expf(s[m] - mx);
    s[m] = e;
    lsum += e;
  }
  red[threadIdx.x] = lsum;
  __syncthreads();
  for (int w = 128; w > 0; w >>= 1) {
    if (threadIdx.x < w) red[threadIdx.x] += red[threadIdx.x + w];
    __syncthreads();
  }
  float inv = 1.f / red[0];
  for (int m = threadIdx.x; m < NN; m += 256) A[(size_t)n * NN + m] = s[m] * inv;
}

// ---- C(NN x cols) = A @ V ; f32, 64x64 tile (prologue only, for A^2) ----
#define TM 64
#define TK 32
__global__ __launch_bounds__(256) void kg(const float* __restrict__ A,
                                          const float* __restrict__ V,
                                          float* __restrict__ C, int cols) {
  __shared__ float As[TK][TM + 1];
  __shared__ float Bs[TK][TM + 1];
  int r0 = blockIdx.x * TM;
  int c0 = blockIdx.y * TM;
  int tid = threadIdx.x;
  int tx = tid % 16;
  int ty = tid / 16;
  float acc[4][4];
#pragma unroll
  for (int i = 0; i < 4; ++i)
#pragma unroll
    for (int j = 0; j < 4; ++j) acc[i][j] = 0.f;
  for (int k0 = 0; k0 < NN; k0 += TK) {
    for (int i = tid; i < TM * TK; i += 256) {
      int rr = i / TK, kk = i % TK;
      int gr = r0 + rr, gk = k0 + kk;
      As[kk][rr] = (gr < NN && gk < NN) ? A[(size_t)gr * NN + gk] : 0.f;
    }
    for (int i = tid; i < TK * TM; i += 256) {
      int kk = i / TM, cc = i % TM;
      int gk = k0 + kk, gc = c0 + cc;
      Bs[kk][cc] = (gk < NN && gc < cols) ? V[(size_t)gk * cols + gc] : 0.f;
    }
    __syncthreads();
#pragma unroll 4
    for (int kk = 0; kk < TK; ++kk) {
      float a[4], b[4];
#pragma unroll
      for (int i = 0; i < 4; ++i) a[i] = As[kk][ty * 4 + i];
#pragma unroll
      for (int j = 0; j < 4; ++j) b[j] = Bs[kk][tx * 4 + j];
#pragma unroll
      for (int i = 0; i < 4; ++i)
#pragma unroll
        for (int j = 0; j < 4; ++j) acc[i][j] += a[i] * b[j];
    }
    __syncthreads();
  }
#pragma unroll
  for (int i = 0; i < 4; ++i) {
    int gr = r0 + ty * 4 + i;
    if (gr >= NN) continue;
#pragma unroll
    for (int j = 0; j < 4; ++j) {
      int gc = c0 + tx * 4 + j;
      if (gc < cols) C[(size_t)gr * cols + gc] = acc[i][j];
    }
  }
}

// ---- build split M = [A ; 2A^2 - I] as f16 hi + lo/2048 ----
__global__ void ksplitM(const float* __restrict__ A, const float* __restrict__ A2,
                        f16* __restrict__ Mh, f16* __restrict__ Ml) {
  int i = blockIdx.x * 256 + threadIdx.x;
  if (i >= MR * NN) return;
  int m = i / NN;
  int k = i % NN;
  float v;
  if (m < NN) v = A[(size_t)m * NN + k];
  else {
    int mm = m - NN;
    v = 2.f * A2[(size_t)mm * NN + k] - (mm == k ? 1.f : 0.f);
  }
  f16 hi, lo;
  split16(v, hi, lo);
  Mh[i] = hi;
  Ml[i] = lo;
}

// ---- split+transpose: V f32 [2000][cols] -> Th/Tl f16 [cols][2000] ----
__global__ __launch_bounds__(256) void kconvT(const float* __restrict__ V,
                                              f16* __restrict__ Th,
                                              f16* __restrict__ Tl, int cols) {
  __shared__ float sh[32][33];
  int k0 = blockIdx.x * 32;
  int c0 = blockIdx.y * 32;
  int tx = threadIdx.x % 32;
  int ty = threadIdx.x / 32;  // 0..7
#pragma unroll
  for (int i = 0; i < 4; ++i) {
    int r = k0 + ty + i * 8;
    int c = c0 + tx;
    sh[ty + i * 8][tx] = (r < NN && c < cols) ? V[(size_t)r * cols + c] : 0.f;
  }
  __syncthreads();
#pragma unroll
  for (int i = 0; i < 4; ++i) {
    int cc = c0 + ty + i * 8;
    int kk = k0 + tx;
    if (cc < cols && kk < NN) {
      f16 hi, lo;
      split16(sh[tx][ty + i * 8], hi, lo);
      Th[(size_t)cc * NN + kk] = hi;
      Tl[(size_t)cc * NN + kk] = lo;
    }
  }
}

// ---- MFMA GEMM: FROZEN at the best-measured config (53.85 ms, R8).
// 128x128 tile, 4 waves (2x2), per-wave 64x64, dual f32 accumulators,
// single-buffer LDS, __syncthreads per K-step, XCD bijective swizzle.
// Probe record: R1 counted-vmcnt dbuf = null; R3 128x256 1-block/CU = -35%;
// R4 single-acc 12w/CU = null; R5/R6 256x128 = -65% (VGPR spill);
// R9 drop-A-correction = FAIL (absmax 1.5 — recurrence amplifies ~3000x;
// BOTH correction passes are numerically load-bearing). Do not touch.
#define KT 32
__global__ __launch_bounds__(256, 2) void kmm(const f16* __restrict__ Mh,
                                              const f16* __restrict__ Ml,
                                              const f16* __restrict__ Bh,
                                              const f16* __restrict__ Bl,
                                              float* __restrict__ C1,
                                              float* __restrict__ C2, int cols) {
  __shared__ __align__(16) f16 Ash[128 * KT];
  __shared__ __align__(16) f16 Asl[128 * KT];
  __shared__ __align__(16) f16 Bsh[128 * KT];
  __shared__ __align__(16) f16 Bsl[128 * KT];
  int tid = threadIdx.x;
  int lane = tid & 63;
  int wave = tid >> 6;
  int wr = wave >> 1;   // 0..1
  int wc = wave & 1;    // 0..1
  // XCD swizzle: bijective contiguous-chunk remap (m204) for B-panel L2 reuse.
  int gx = gridDim.x;
  int nwg = gx * gridDim.y;
  int wg = blockIdx.y * gx + blockIdx.x;
  int q = nwg >> 3, r = nwg & 7;
  int xcd = wg & 7, lid = wg >> 3;
  int swz = (xcd < r ? xcd * (q + 1) : r * (q + 1) + (xcd - r) * q) + lid;
  int bx = swz % gx;
  int by = swz / gx;
  floatx4 acc0[4][4], acc1[4][4];
#pragma unroll
  for (int i = 0; i < 4; ++i)
#pragma unroll
    for (int j = 0; j < 4; ++j) {
      acc0[i][j] = (floatx4){0.f, 0.f, 0.f, 0.f};
      acc1[i][j] = (floatx4){0.f, 0.f, 0.f, 0.f};
    }
  const frag8h zf = {0, 0, 0, 0, 0, 0, 0, 0};

  auto comp = [&]() {
    frag8h ah[4], al[4], bh[4], bl[4];
#pragma unroll
    for (int mi = 0; mi < 4; ++mi) {
      int jr = wr * 4 + mi;                       // region index (16 rows each)
      ah[mi] = *(const frag8h*)(&Ash[jr * 512 + lane * 8]);
      al[mi] = *(const frag8h*)(&Asl[jr * 512 + lane * 8]);
    }
#pragma unroll
    for (int ni = 0; ni < 4; ++ni) {
      int jc = wc * 4 + ni;
      bh[ni] = *(const frag8h*)(&Bsh[jc * 512 + lane * 8]);
      bl[ni] = *(const frag8h*)(&Bsl[jc * 512 + lane * 8]);
    }
#pragma unroll
    for (int mi = 0; mi < 4; ++mi)
#pragma unroll
      for (int ni = 0; ni < 4; ++ni) {
        acc0[mi][ni] = __builtin_amdgcn_mfma_f32_16x16x32_f16(ah[mi], bh[ni], acc0[mi][ni], 0, 0, 0);
        acc1[mi][ni] = __builtin_amdgcn_mfma_f32_16x16x32_f16(ah[mi], bl[ni], acc1[mi][ni], 0, 0, 0);
        acc1[mi][ni] = __builtin_amdgcn_mfma_f32_16x16x32_f16(al[mi], bh[ni], acc1[mi][ni], 0, 0, 0);
      }
  };

  const int lr = lane & 15;   // row within region this lane stages
  const int lq = lane >> 4;   // k-chunk this lane stages
  // fast path: full 32-k tiles via global_load_lds
  for (int k0 = 0; k0 + KT <= NN; k0 += KT) {
#pragma unroll
    for (int jj = 0; jj < 2; ++jj) {
      int j = wave * 2 + jj;            // region 0..7
      int r2 = j * 16 + lr;
      size_t ko = (size_t)k0 + lq * 8;
      int gra = bx * 128 + r2;
      if (gra < MR) {
        gll16(Mh + (size_t)gra * NN + ko, Ash + j * 512);
        gll16(Ml + (size_t)gra * NN + ko, Asl + j * 512);
      }
      int grb = by * 128 + r2;
      if (grb < cols) {
        gll16(Bh + (size_t)grb * NN + ko, Bsh + j * 512);
        gll16(Bl + (size_t)grb * NN + ko, Bsl + j * 512);
      }
    }
    __syncthreads();
    comp();
    __syncthreads();
  }
  // tail (k0 = 1984, 16 valid k): guarded VGPR staging, same slot layout
  {
    int k0 = (NN / KT) * KT;
    if (k0 < NN) {
      for (int c = tid; c < 512; c += 256) {
        int j = c >> 6;          // region
        int ll = c & 63;         // slot within region
        int qq = ll >> 4;
        int rr = ll & 15;
        int r2 = j * 16 + rr;
        int gk = k0 + qq * 8;
        bool kok = (gk + 8 <= NN);
        int gra = bx * 128 + r2;
        bool aok = kok && (gra < MR);
        size_t ga = (size_t)gra * NN + gk;
        *(frag8h*)(&Ash[c * 8]) = aok ? *(const frag8h*)(Mh + ga) : zf;
        *(frag8h*)(&Asl[c * 8]) = aok ? *(const frag8h*)(Ml + ga) : zf;
        int grb = by * 128 + r2;
        bool bok = kok && (grb < cols);
        size_t gb = (size_t)grb * NN + gk;
        *(frag8h*)(&Bsh[c * 8]) = bok ? *(const frag8h*)(Bh + gb) : zf;
        *(frag8h*)(&Bsl[c * 8]) = bok ? *(const frag8h*)(Bl + gb) : zf;
      }
      __syncthreads();
      comp();
      __syncthreads();
    }
  }
  // store: C/D layout col = lane&15, row = (lane>>4)*4 + reg
#pragma unroll
  for (int mi = 0; mi < 4; ++mi) {
#pragma unroll
    for (int ni = 0; ni < 4; ++ni) {
#pragma unroll
      for (int reg = 0; reg < 4; ++reg) {
        int row = bx * 128 + wr * 64 + mi * 16 + (lane >> 4) * 4 + reg;
        int col = by * 128 + wc * 64 + ni * 16 + (lane & 15);
        if (col >= cols || row >= MR) continue;
        float v = acc0[mi][ni][reg] + acc1[mi][ni][reg] * ISCL;
        if (row < NN) C1[(size_t)row * cols + col] = v;
        else C2[(size_t)(row - NN) * cols + col] = v;
      }
    }
  }
}

// ---- xb[n*CB + bb] = src[((b0+bb)*TT + t)*NN + n] (tight path) ----
__global__ void kx(const float* __restrict__ src, float* __restrict__ xb,
                   int t, int b0, int CB) {
  int i = blockIdx.x * 256 + threadIdx.x;
  if (i >= NN * CB) return;
  int bb = i % CB;
  int n = i / CB;
  xb[i] = fin(src[((size_t)(b0 + bb) * TT + t) * NN + n]);
}

// ---- batched: xa[n*(TT*CB) + t*CB + bb] = src[((b0+bb)*TT + t)*NN + n] ----
__global__ void kxa(const float* __restrict__ src, float* __restrict__ xa,
                    int b0, int CB) {
  int i = blockIdx.x * 256 + threadIdx.x;
  if (i >= NN * TT * CB) return;
  int bb = i % CB;
  int t = (i / CB) % TT;
  int n = i / (CB * TT);
  xa[i] = fin(src[((size_t)(b0 + bb) * TT + t) * NN + n]);
}

// ---- zb[i] *= h[i] (legacy path only) ----
__global__ void kmulz(float* __restrict__ zb, const float* __restrict__ h, int n) {
  int i = blockIdx.x * 256 + threadIdx.x;
  if (i < n) zb[i] = zb[i] * h[i];
}

// ---- precompute per-node combined weights W[n,k,c,o] = sum_d E[n,d]*wp[d,k,c,o].
__global__ __launch_bounds__(256) void kwc(const float* __restrict__ E,
                                           const float* __restrict__ wp,
                                           int Ctot, int O, float* __restrict__ W) {
  __shared__ float esm[DD];
  int n = blockIdx.x;
  int tid = threadIdx.x;
  if (tid < DD) esm[tid] = fin(E[n * DD + tid]);
  __syncthreads();
  int total = 3 * Ctot * O;
  for (int i = tid; i < total; i += 256) {
    int o = i % O;
    int rc = i / O;              // k*Ctot + crow
    int k = rc / Ctot;
    int crow = rc - k * Ctot;
    float wa = 0.f;
#pragma unroll
    for (int d = 0; d < DD; ++d)
      wa += esm[d] * fin(wp[((size_t)(d * 3 + k) * Ctot + crow) * O + o]);
    W[((size_t)(n * 3 + k) * Ctot + crow) * O + o] = wa;
  }
}

// ---- gconv (chunk=16). ldn = per-node row stride of x. ----
template <int O, int CB>
__global__ __launch_bounds__(256) void kgc(
    const float* __restrict__ x0, const float* __restrict__ x1, const float* __restrict__ x2,
    const float* __restrict__ wp, const float* __restrict__ pW,
    int Ctot, int base_c, int nC, int ldn,
    const float* __restrict__ E, const float* __restrict__ bp,
    int act, int accum, float* outA, float* outB,
    int update, const float* __restrict__ rb, float* hio) {
  __shared__ float xs[16][CB + 1];
  __shared__ float ws[16][O];
  __shared__ float esm[DD];
  int n = blockIdx.x;
  int tid = threadIdx.x;
  int to = tid % 16;
  int tb = tid / 16;
  if (tid < DD) esm[tid] = fin(E[n * DD + tid]);
  __syncthreads();
  constexpr int NO = O / 16;
  constexpr int NB = CB / 16;
  float acc[NB][NO];
#pragma unroll
  for (int i = 0; i < NB; ++i)
#pragma unroll
    for (int j = 0; j < NO; ++j) acc[i][j] = 0.f;
  const size_t nb = (size_t)n * CB;
  const size_t nx = (size_t)n * ldn;
  for (int k = 0; k < 3; ++k) {
    const float* xk = (k == 0) ? x0 : (k == 1) ? x1 : x2;
    for (int c0 = 0; c0 < nC; c0 += 16) {
      int chunk = (nC - c0 < 16) ? (nC - c0) : 16;
      for (int i = tid; i < chunk * CB; i += 256) {
        int cc = i % chunk;
        int b = i / chunk;
        xs[cc][b] = xk[nx + (size_t)b * nC + c0 + cc];
      }
      if (pW) {
        const float* wrow = pW + ((size_t)(n * 3 + k) * Ctot + base_c + c0) * O;
        for (int i = tid; i < chunk * O; i += 256) {
          int o = i % O;
          int cc = i / O;
          ws[cc][o] = wrow[(size_t)cc * O + o];
        }
      } else {
        for (int i = tid; i < chunk * O; i += 256) {
          int o = i % O;
          int cc = i / O;
          int crow = base_c + c0 + cc;
          float wa = 0.f;
#pragma unroll
          for (int d = 0; d < DD; ++d)
            wa += esm[d] * fin(wp[((size_t)(d * 3 + k) * Ctot + crow) * O + o]);
          ws[cc][o] = wa;
        }
      }
      __syncthreads();
      for (int cc = 0; cc < chunk; ++cc) {
        float xv[NB];
#pragma unroll
        for (int i = 0; i < NB; ++i) xv[i] = xs[cc][tb + 16 * i];
#pragma unroll
        for (int j = 0; j < NO; ++j) {
          float wv = ws[cc][to + 16 * j];
#pragma unroll
          for (int i = 0; i < NB; ++i) acc[i][j] += xv[i] * wv;
        }
      }
      __syncthreads();
    }
  }
#pragma unroll
  for (int i2 = 0; i2 < NB; ++i2) {
    int b = tb + 16 * i2;
#pragma unroll
    for (int j = 0; j < NO; ++j) {
      int o = to + 16 * j;
      float r = acc[i2][j];
      float* dst = (o < HH || !outB) ? (outA + (nb + b) * HH + (o % HH))
                                     : (outB + (nb + b) * HH + (o - HH));
      if (accum) r += *dst;
      if (bp) {
        float ba = 0.f;
#pragma unroll
        for (int d = 0; d < DD; ++d) ba += esm[d] * fin(bp[d * O + o]);
        r += ba;
      }
      r = fin(r);
      if (act == 1) r = sigmoid_safe(r);
      else if (act == 2) r = tanh_safe(r);
      if (update) {
        float rg = rb[(nb + b) * HH + o];
        float hold = hio[(nb + b) * HH + o];
        hio[(nb + b) * HH + o] = rg * hold + (1.f - rg) * r;
      } else {
        *dst = r;
      }
    }
  }
}

// ---- fused kernel: gate(h-part) + gate(x-part) + update(x-part), with the
// z*h elementwise product fused into the epilogue (hmul = the layer's h).
template <int CB>
__global__ __launch_bounds__(256) void kgf(
    const float* __restrict__ A0, const float* __restrict__ A1, const float* __restrict__ A2,
    int nCA, int baseA, int ldA,
    const float* __restrict__ B0, const float* __restrict__ B1, const float* __restrict__ B2,
    int nCB, int baseB, int ldB,
    const float* __restrict__ wpg, const float* __restrict__ pWg,
    const float* __restrict__ bpg,
    const float* __restrict__ wpu, const float* __restrict__ pWu,
    int Ctot, const float* __restrict__ E, const float* __restrict__ hmul,
    float* __restrict__ zb, float* __restrict__ rbf, float* __restrict__ hc) {
  __shared__ float xs[16][CB + 1];
  __shared__ float wsg[16][128];
  __shared__ float wsu[16][64];
  __shared__ float esm[DD];
  int n = blockIdx.x;
  int tid = threadIdx.x;
  int to = tid % 16;
  int tb = tid / 16;
  if (tid < DD) esm[tid] = fin(E[n * DD + tid]);
  __syncthreads();
  constexpr int NB = CB / 16;
  float accg[NB][8];
  float accu[NB][4];
#pragma unroll
  for (int i = 0; i < NB; ++i) {
#pragma unroll
    for (int j = 0; j < 8; ++j) accg[i][j] = 0.f;
#pragma unroll
    for (int j = 0; j < 4; ++j) accu[i][j] = 0.f;
  }
  const size_t nb = (size_t)n * CB;

  // ---- pass A: gate only ----
  {
    const size_t nx = (size_t)n * ldA;
    for (int k = 0; k < 3; ++k) {
      const float* xk = (k == 0) ? A0 : (k == 1) ? A1 : A2;
      for (int c0 = 0; c0 < nCA; c0 += 16) {
        int chunk = (nCA - c0 < 16) ? (nCA - c0) : 16;
        for (int i = tid; i < chunk * CB; i += 256) {
          int cc = i % chunk;
          int b = i / chunk;
          xs[cc][b] = xk[nx + (size_t)b * nCA + c0 + cc];
        }
        if (pWg) {
          const float* wrow = pWg + ((size_t)(n * 3 + k) * Ctot + baseA + c0) * 128;
          for (int i = tid; i < chunk * 128; i += 256) {
            int o = i % 128;
            int cc = i / 128;
            wsg[cc][o] = wrow[(size_t)cc * 128 + o];
          }
        } else {
          for (int i = tid; i < chunk * 128; i += 256) {
            int o = i % 128;
            int cc = i / 128;
            int crow = baseA + c0 + cc;
            float wa = 0.f;
#pragma unroll
            for (int d = 0; d < DD; ++d)
              wa += esm[d] * fin(wpg[((size_t)(d * 3 + k) * Ctot + crow) * 128 + o]);
            wsg[cc][o] = wa;
          }
        }
        __syncthreads();
        for (int cc = 0; cc < chunk; ++cc) {
          float xv[NB];
#pragma unroll
          for (int i = 0; i < NB; ++i) xv[i] = xs[cc][tb + 16 * i];
#pragma unroll
          for (int j = 0; j < 8; ++j) {
            float wv = wsg[cc][to + 16 * j];
#pragma unroll
            for (int i = 0; i < NB; ++i) accg[i][j] += xv[i] * wv;
          }
        }
        __syncthreads();
      }
    }
  }
  // ---- pass B: gate + update ----
  {
    const size_t nx = (size_t)n * ldB;
    for (int k = 0; k < 3; ++k) {
      const float* xk = (k == 0) ? B0 : (k == 1) ? B1 : B2;
      for (int c0 = 0; c0 < nCB; c0 += 16) {
        int chunk = (nCB - c0 < 16) ? (nCB - c0) : 16;
        for (int i = tid; i < chunk * CB; i += 256) {
          int cc = i % chunk;
          int b = i / chunk;
          xs[cc][b] = xk[nx + (size_t)b * nCB + c0 + cc];
        }
        if (pWg) {
          const float* wrow = pWg + ((size_t)(n * 3 + k) * Ctot + baseB + c0) * 128;
          for (int i = tid; i < chunk * 128; i += 256) {
            int o = i % 128;
            int cc = i / 128;
            wsg[cc][o] = wrow[(size_t)cc * 128 + o];
          }
        } else {
          for (int i = tid; i < chunk * 128; i += 256) {
            int o = i % 128;
            int cc = i / 128;
            int crow = baseB + c0 + cc;
            float wa = 0.f;
#pragma unroll
            for (int d = 0; d < DD; ++d)
              wa += esm[d] * fin(wpg[((size_t)(d * 3 + k) * Ctot + crow) * 128 + o]);
            wsg[cc][o] = wa;
          }
        }
        if (pWu) {
          const float* wrow = pWu + ((size_t)(n * 3 + k) * Ctot + baseB + c0) * 64;
          for (int i = tid; i < chunk * 64; i += 256) {
            int o = i % 64;
            int cc = i / 64;
            wsu[cc][o] = wrow[(size_t)cc * 64 + o];
          }
        } else {
          for (int i = tid; i < chunk * 64; i += 256) {
            int o = i % 64;
            int cc = i / 64;
            int crow = baseB + c0 + cc;
            float wa = 0.f;
#pragma unroll
            for (int d = 0; d < DD; ++d)
              wa += esm[d] * fin(wpu[((size_t)(d * 3 + k) * Ctot + crow) * 64 + o]);
            wsu[cc][o] = wa;
          }
        }
        __syncthreads();
        for (int cc = 0; cc < chunk; ++cc) {
          float xv[NB];
#pragma unroll
          for (int i = 0; i < NB; ++i) xv[i] = xs[cc][tb + 16 * i];
#pragma unroll
          for (int j = 0; j < 8; ++j) {
            float wv = wsg[cc][to + 16 * j];
#pragma unroll
            for (int i = 0; i < NB; ++i) accg[i][j] += xv[i] * wv;
          }
#pragma unroll
          for (int j = 0; j < 4; ++j) {
            float wv = wsu[cc][to + 16 * j];
#pragma unroll
            for (int i = 0; i < NB; ++i) accu[i][j] += xv[i] * wv;
          }
        }
        __syncthreads();
      }
    }
  }
  // ---- epilogue ----
#pragma unroll
  for (int i2 = 0; i2 < NB; ++i2) {
    int b = tb + 16 * i2;
#pragma unroll
    for (int j = 0; j < 8; ++j) {
      int o = to + 16 * j;
      float r = accg[i2][j];
      float ba = 0.f;
#pragma unroll
      for (int d = 0; d < DD; ++d) ba += esm[d] * fin(bpg[d * 128 + o]);
      r = fin(r + ba);
      r = sigmoid_safe(r);
      if (o < HH) zb[(nb + b) * HH + o] = r * hmul[(nb + b) * HH + o];
      else rbf[(nb + b) * HH + (o - HH)] = r;
    }
#pragma unroll
    for (int j = 0; j < 4; ++j) {
      int o = to + 16 * j;
      hc[(nb + b) * HH + o] = fin(accu[i2][j]);
    }
  }
}

// ---- out[(b0+bb), o, n] = sum_h h1[n,bb,h]*cw[o*H+h] + cb[o] ----
__global__ void kfin(const float* __restrict__ h1, const float* __restrict__ cw,
                     const float* __restrict__ cb, float* __restrict__ out,
                     int b0, int CB) {
  int idx = blockIdx.x * 256 + threadIdx.x;
  if (idx >= CB * TT * NN) return;
  int n = idx % NN;
  int o = (idx / NN) % TT;
  int bb = idx / (NN * TT);
  const float* hp = h1 + ((size_t)n * CB + bb) * HH;
  float acc = fin(cb[o]);
#pragma unroll
  for (int hh = 0; hh < HH; ++hh) acc += hp[hh] * fin(cw[o * HH + hh]);
  out[((size_t)(b0 + bb) * TT + o) * NN + n] = fin(acc);
}

// Scheduling notes:
//  * h0 mutated only at end of layer 0 -> cache its chain (P1c/P2c, roomy).
//  * t=0: h0=h1=0, zb=z*h=0 -> zero-input chains replaced by zero buffers.
//  * kgf fuses {gate-h, gate-x, update-x, z*=h} per layer-timestep.
//  * h0/h1 contiguous -> single kzero over both.
template <int CB>
static void run_chunks(const float* src, const float* E,
                       const float* gwp0, const float* gbp0,
                       const float* uwp0, const float* ubp0,
                       const float* gwp1, const float* gbp1,
                       const float* uwp1, const float* ubp1,
                       const float* cw, const float* cb,
                       float* out, f16* Mh, f16* Ml,
                       const float* pg0, const float* pu0,
                       const float* pg1, const float* pu1,
                       char* wsp, size_t off0, bool roomy, hipStream_t stream) {
  size_t off = off0;
  auto allocf = [&](size_t nelem) {
    float* p = (float*)(wsp + off);
    off += (nelem * 4 + 255) & ~(size_t)255;
    return p;
  };
  auto alloch = [&](size_t nelem) {
    f16* p = (f16*)(wsp + off);
    off += (nelem * 2 + 255) & ~(size_t)255;
    return p;
  };
  const int C = CB * HH;
  const int XC = TT * CB;
  const size_t NC = (size_t)NN * C;
  float* P1  = allocf(NC);
  float* P2  = allocf(NC);
  float* h0  = allocf(NC);   // h0,h1 contiguous (NC*4 is 256-divisible)
  float* h1  = allocf(NC);
  float* zb  = allocf(NC);
  float* rbf = allocf(NC);
  float* hc  = allocf(NC);
  f16* vh = alloch(NC);
  f16* vl = alloch(NC);
  float *P1c = nullptr, *P2c = nullptr;
  float *xa = nullptr, *xb1a = nullptr, *xb2a = nullptr;
  float *xb0 = nullptr, *xb1 = nullptr, *xb2 = nullptr;
  f16 *xth, *xtl;
  if (roomy) {
    P1c = allocf(NC);
    P2c = allocf(NC);
    xa   = allocf((size_t)NN * XC);
    xb1a = allocf((size_t)NN * XC);
    xb2a = allocf((size_t)NN * XC);
    xth = alloch((size_t)NN * XC);
    xtl = alloch((size_t)NN * XC);
  } else {
    xb0 = allocf((size_t)NN * CB);
    xb1 = allocf((size_t)NN * CB);
    xb2 = allocf((size_t)NN * CB);
    xth = alloch((size_t)NN * CB);
    xtl = alloch((size_t)NN * CB);
  }

  const int EW = (int)((NC + 255) / 256);
  const dim3 gConv((NN + 31) / 32, (C + 31) / 32);
  const dim3 gMM((MR + 127) / 128, (C + 127) / 128);
  float* nul = nullptr;

  auto chain_to = [&](const float* V, float* D1, float* D2) {
    kconvT<<<gConv, 256, 0, stream>>>(V, vh, vl, C);
    kmm<<<gMM, 256, 0, stream>>>(Mh, Ml, vh, vl, D1, D2, C);
  };

  for (int b0 = 0; b0 < BB; b0 += CB) {
    kzero<<<2 * EW, 256, 0, stream>>>(h0, (int)(2 * NC));   // h0+h1 contiguous
    if (roomy) {
      kxa<<<((NN * XC) + 255) / 256, 256, 0, stream>>>(src, xa, b0, CB);
      dim3 gcx((NN + 31) / 32, (XC + 31) / 32);
      kconvT<<<gcx, 256, 0, stream>>>(xa, xth, xtl, XC);
      dim3 gmx((MR + 127) / 128, (XC + 127) / 128);
      kmm<<<gmx, 256, 0, stream>>>(Mh, Ml, xth, xtl, xb1a, xb2a, XC);
    }
    for (int t = 0; t < TT; ++t) {
      const bool tz = (t == 0);
      const float *xt0, *xt1, *xt2;
      int xln;
      if (roomy) {
        xt0 = xa + t * CB;
        xt1 = xb1a + t * CB;
        xt2 = xb2a + t * CB;
        xln = XC;
      } else {
        kx<<<(NN * CB + 255) / 256, 256, 0, stream>>>(src, xb0, t, b0, CB);
        dim3 gcx((NN + 31) / 32, (CB + 31) / 32);
        kconvT<<<gcx, 256, 0, stream>>>(xb0, xth, xtl, CB);
        dim3 gmx((MR + 127) / 128, (CB + 127) / 128);
        kmm<<<gmx, 256, 0, stream>>>(Mh, Ml, xth, xtl, xb1, xb2, CB);
        xt0 = xb0; xt1 = xb1; xt2 = xb2;
        xln = CB;
      }
      // ===== layer 0 (Ctot=65): fused gate+updateX+(z*=h0) =====
      const float *g1, *g2;
      if (tz) { g1 = h0; g2 = h0; }                 // h0 == 0: chains are zero
      else if (roomy) { g1 = P1c; g2 = P2c; }        // cached from prev t layer1
      else { chain_to(h0, P1, P2); g1 = P1; g2 = P2; }
      kgf<CB><<<NN, 256, 0, stream>>>(h0, g1, g2, 64, 1, C,
                                      xt0, xt1, xt2, 1, 0, xln,
                                      gwp0, pg0, gbp0, uwp0, pu0, 65, E, h0,
                                      zb, rbf, hc);
      if (tz) {  // zb = z*0 = 0
        kgc<64, CB><<<NN, 256, 0, stream>>>(zb, zb, zb, uwp0, pu0, 65, 1, 64, C, E, ubp0,
                                            2, 1, hc, nul, 1, rbf, h0);
      } else {
        chain_to(zb, P1, P2);
        kgc<64, CB><<<NN, 256, 0, stream>>>(zb, P1, P2, uwp0, pu0, 65, 1, 64, C, E, ubp0,
                                            2, 1, hc, nul, 1, rbf, h0);
      }
      // ===== layer 1 (x = h0 new, Ctot=128) =====
      if (roomy) {
        const float *a1, *a2;
        if (tz) { a1 = h1; a2 = h1; }
        else { chain_to(h1, P1, P2); a1 = P1; a2 = P2; }
        chain_to(h0, P1c, P2c);   // also cached for next t layer 0
        kgf<CB><<<NN, 256, 0, stream>>>(h1, a1, a2, 64, 64, C,
                                        h0, P1c, P2c, 64, 0, C,
                                        gwp1, pg1, gbp1, uwp1, pu1, 128, E, h1,
                                        zb, rbf, hc);
      } else {
        if (tz) {
          kgc<128, CB><<<NN, 256, 0, stream>>>(h1, h1, h1, gwp1, pg1, 128, 64, 64, C, E, nullptr,
                                               0, 0, zb, rbf, 0, nul, nul);
        } else {
          chain_to(h1, P1, P2);
          kgc<128, CB><<<NN, 256, 0, stream>>>(h1, P1, P2, gwp1, pg1, 128, 64, 64, C, E, nullptr,
                                               0, 0, zb, rbf, 0, nul, nul);
        }
        chain_to(h0, P1, P2);
        kgc<128, CB><<<NN, 256, 0, stream>>>(h0, P1, P2, gwp1, pg1, 128, 0, 64, C, E, gbp1,
                                             1, 1, zb, rbf, 0, nul, nul);
        kgc<64, CB><<<NN, 256, 0, stream>>>(h0, P1, P2, uwp1, pu1, 128, 0, 64, C, E, nullptr,
                                            0, 0, hc, nul, 0, nul, nul);
        kmulz<<<EW, 256, 0, stream>>>(zb, h1, (int)NC);
      }
      if (tz) {  // zb = z*0 = 0
        kgc<64, CB><<<NN, 256, 0, stream>>>(zb, zb, zb, uwp1, pu1, 128, 64, 64, C, E, ubp1,
                                            2, 1, hc, nul, 1, rbf, h1);
      } else {
        chain_to(zb, P1, P2);
        kgc<64, CB><<<NN, 256, 0, stream>>>(zb, P1, P2, uwp1, pu1, 128, 64, 64, C, E, ubp1,
                                            2, 1, hc, nul, 1, rbf, h1);
      }
    }
    kfin<<<(CB * TT * NN + 255) / 256, 256, 0, stream>>>(h1, cw, cb, out, b0, CB);
  }
}

extern "C" void kernel_launch(void* const* d_in, const int* in_sizes, int n_in,
                              void* d_out, int out_size, void* d_ws, size_t ws_size,
                              hipStream_t stream) {
  const float* src  = (const float*)d_in[0];
  const float* E    = (const float*)d_in[1];
  const float* gwp0 = (const float*)d_in[2];
  const float* gbp0 = (const float*)d_in[3];
  const float* uwp0 = (const float*)d_in[4];
  const float* ubp0 = (const float*)d_in[5];
  const float* gwp1 = (const float*)d_in[6];
  const float* gbp1 = (const float*)d_in[7];
  const float* uwp1 = (const float*)d_in[8];
  const float* ubp1 = (const float*)d_in[9];
  const float* cw   = (const float*)d_in[10];
  const float* cb   = (const float*)d_in[11];
  float* out = (float*)d_out;
  (void)in_sizes; (void)n_in; (void)out_size;

  char* wsp = (char*)d_ws;
  size_t off = 0;
  f16* Mh = (f16*)(wsp + off); off += ((size_t)MR * NN * 2 + 255) & ~(size_t)255;
  f16* Ml = (f16*)(wsp + off); off += ((size_t)MR * NN * 2 + 255) & ~(size_t)255;

  // Optional precomputed combined-weight tensors (time-invariant, launch-lifetime).
  const size_t szg1 = (size_t)NN * 3 * 128 * 128;  // floats
  const size_t szu1 = (size_t)NN * 3 * 128 * 64;
  const size_t szg0 = (size_t)NN * 3 * 65 * 128;
  const size_t szu0 = (size_t)NN * 3 * 65 * 64;
  float *pg0 = nullptr, *pu0 = nullptr, *pg1 = nullptr, *pu1 = nullptr;
  bool wantAll = ws_size >= (size_t)1350 * 1000 * 1000;
  bool wantL1  = ws_size >= (size_t)1030 * 1000 * 1000;
  if (wantAll || wantL1) {
    pg1 = (float*)(wsp + off); off += (szg1 * 4 + 255) & ~(size_t)255;
    pu1 = (float*)(wsp + off); off += (szu1 * 4 + 255) & ~(size_t)255;
    if (wantAll) {
      pg0 = (float*)(wsp + off); off += (szg0 * 4 + 255) & ~(size_t)255;
      pu0 = (float*)(wsp + off); off += (szu0 * 4 + 255) & ~(size_t)255;
    }
  }
  size_t off0 = off;  // chunk area starts here
  // transient prologue buffers overlap the chunk area (dead before chunks start)
  float* A  = (float*)(wsp + off0);
  float* A2 = (float*)(wsp + off0 + (((size_t)NN * NN * 4 + 255) & ~(size_t)255));

  ka<<<NN, 256, 0, stream>>>(E, A);
  {
    dim3 g((NN + TM - 1) / TM, (NN + TM - 1) / TM);
    kg<<<g, 256, 0, stream>>>(A, A, A2, NN);
  }
  ksplitM<<<(MR * NN + 255) / 256, 256, 0, stream>>>(A, A2, Mh, Ml);
  if (pg1) {
    kwc<<<NN, 256, 0, stream>>>(E, gwp1, 128, 128, pg1);
    kwc<<<NN, 256, 0, stream>>>(E, uwp1, 128, 64, pu1);
  }
  if (pg0) {
    kwc<<<NN, 256, 0, stream>>>(E, gwp0, 65, 128, pg0);
    kwc<<<NN, 256, 0, stream>>>(E, uwp0, 65, 64, pu0);
  }

  // footprints past off0 (chunk area): CB=64 roomy ~353MB, tight ~265MB;
  // CB=32 roomy ~177MB, tight ~133MB; CB=16 roomy ~90MB, tight ~67MB.
  size_t rem = ws_size > off0 ? ws_size - off0 : 0;
  if (rem >= (size_t)368 * 1000 * 1000) {
    run_chunks<64>(src, E, gwp0, gbp0, uwp0, ubp0, gwp1, gbp1, uwp1, ubp1,
                   cw, cb, out, Mh, Ml, pg0, pu0, pg1, pu1, wsp, off0, true, stream);
  } else if (rem >= (size_t)288 * 1000 * 1000) {
    run_chunks<64>(src, E, gwp0, gbp0, uwp0, ubp0, gwp1, gbp1, uwp1, ubp1,
                   cw, cb, out, Mh, Ml, pg0, pu0, pg1, pu1, wsp, off0, false, stream);
  } else if (rem >= (size_t)193 * 1000 * 1000) {
    run_chunks<32>(src, E, gwp0, gbp0, uwp0, ubp0, gwp1, gbp1, uwp1, ubp1,
                   cw, cb, out, Mh, Ml, pg0, pu0, pg1, pu1, wsp, off0, true, stream);
  } else if (rem >= (size_t)153 * 1000 * 1000) {
    run_chunks<32>(src, E, gwp0, gbp0, uwp0, ubp0, gwp1, gbp1, uwp1, ubp1,
                   cw, cb, out, Mh, Ml, pg0, pu0, pg1, pu1, wsp, off0, false, stream);
  } else if (rem >= (size_t)98 * 1000 * 1000) {
    run_chunks<16>(src, E, gwp0, gbp0, uwp0, ubp0, gwp1, gbp1, uwp1, ubp1,
                   cw, cb, out, Mh, Ml, pg0, pu0, pg1, pu1, wsp, off0, true, stream);
  } else {
    run_chunks<16>(src, E, gwp0, gbp0, uwp0, ubp0, gwp1, gbp1, uwp1, ubp1,
                   cw, cb, out, Mh, Ml, pg0, pu0, pg1, pu1, wsp, off0, false, stream);
  }
}